// Round 1
// baseline (2748.290 us; speedup 1.0000x reference)
//
#include <hip/hip_runtime.h>
#include <hip/hip_bf16.h>
#include <math.h>

#define H 8
#define D 128
#define HID 1024
#define KCONV 4

// ---------------- GEMM: C[M,N] = A[M,K] * B[N,K]^T ----------------
// 64x64 tile, BK=16, 256 threads, 4x4 per thread, fp32.
__global__ __launch_bounds__(256) void gemm_nt(const float* __restrict__ A,
                                               const float* __restrict__ B,
                                               float* __restrict__ C,
                                               int M, int N, int K)
{
    __shared__ __align__(16) float As[16][68];
    __shared__ __align__(16) float Bs[16][68];
    int tid = threadIdx.x;
    int tx = tid % 16;
    int ty = tid / 16;
    int rowBase = blockIdx.y * 64;
    int colBase = blockIdx.x * 64;
    int lk = tid % 16;   // k offset within BK
    int lr = tid / 16;   // row 0..15 (+16 per rep)
    float acc[4][4] = {};

    for (int k0 = 0; k0 < K; k0 += 16) {
#pragma unroll
        for (int rep = 0; rep < 4; ++rep) {
            int r = lr + rep * 16;
            As[lk][r] = A[(size_t)(rowBase + r) * K + k0 + lk];
            Bs[lk][r] = B[(size_t)(colBase + r) * K + k0 + lk];
        }
        __syncthreads();
#pragma unroll
        for (int kk = 0; kk < 16; ++kk) {
            float4 a4 = *(const float4*)&As[kk][ty * 4];
            float4 b4 = *(const float4*)&Bs[kk][tx * 4];
            float av[4] = {a4.x, a4.y, a4.z, a4.w};
            float bv[4] = {b4.x, b4.y, b4.z, b4.w};
#pragma unroll
            for (int i = 0; i < 4; ++i)
#pragma unroll
                for (int j = 0; j < 4; ++j)
                    acc[i][j] += av[i] * bv[j];
        }
        __syncthreads();
    }
#pragma unroll
    for (int i = 0; i < 4; ++i) {
        float4 o = make_float4(acc[i][0], acc[i][1], acc[i][2], acc[i][3]);
        *(float4*)&C[(size_t)(rowBase + ty * 4 + i) * N + colBase + tx * 4] = o;
    }
}

// ---------------- beta = sigmoid(x @ Wb^T), Wb: (H, HID) ----------------
__global__ __launch_bounds__(256) void beta_kernel(const float* __restrict__ x,
                                                   const float* __restrict__ Wb,
                                                   float* __restrict__ beta)
{
    int row = blockIdx.x;            // b*T + t
    int tid = threadIdx.x;
    int h = tid >> 5;                // 8 heads x 32 lanes
    int lane = tid & 31;
    const float* xr = x + (size_t)row * HID;
    const float* wr = Wb + (size_t)h * HID;
    float acc = 0.f;
    for (int k = lane; k < HID; k += 32) acc += xr[k] * wr[k];
#pragma unroll
    for (int s = 16; s > 0; s >>= 1) acc += __shfl_xor(acc, s, 64);
    if (lane == 0) beta[(size_t)row * H + h] = 1.f / (1.f + expf(-acc));
}

// ---------------- depthwise causal conv (K=4) + SiLU (+ rmsnorm*scale) ----------------
// mode 0: v (silu only); mode 1/2: q/k (silu + rmsnorm + scale)
__global__ __launch_bounds__(128) void conv_kernel(const float* __restrict__ P,
                                                   const float* __restrict__ w,
                                                   float* __restrict__ out,
                                                   int mode, float scale, int T)
{
    int bid = blockIdx.x;            // (b*T + t)*H + h
    int h = bid % H;
    int t = (bid / H) % T;
    int b = bid / (H * T);
    int d = threadIdx.x;
    int c = h * D + d;
    const float* base = P + (size_t)b * T * HID;
    float acc = 0.f;
#pragma unroll
    for (int j = 0; j < KCONV; ++j) {
        int tt = t - (KCONV - 1) + j;
        float xv = (tt >= 0) ? base[(size_t)tt * HID + c] : 0.f;
        acc += xv * w[c * KCONV + j];
    }
    float y = acc / (1.f + expf(-acc));   // SiLU
    if (mode) {
        __shared__ float red[2];
        float ss = y * y;
#pragma unroll
        for (int s = 32; s > 0; s >>= 1) ss += __shfl_xor(ss, s, 64);
        if ((threadIdx.x & 63) == 0) red[threadIdx.x >> 6] = ss;
        __syncthreads();
        float tot = red[0] + red[1];
        float r = rsqrtf(tot * (1.f / D) + 1e-6f);
        y = y * r * scale;
    }
    out[(size_t)bid * D + d] = y;
}

// ---------------- a_logits -> exp(g) in place ----------------
__global__ void eg_kernel(float* __restrict__ a, const float* __restrict__ A_log,
                          const float* __restrict__ dt_bias, int n)
{
    int i = blockIdx.x * blockDim.x + threadIdx.x;
    if (i >= n) return;
    int d = i % D;
    int h = (i / D) % H;
    float z = a[i] + dt_bias[h * D + d];
    float sp = (z > 20.f) ? z : log1pf(expf(z));
    a[i] = expf(-expf(A_log[h]) * sp);
}

// ---------------- gated delta-rule recurrence ----------------
// one block per (b,h); 256 threads: col = tid>>1 (value dim), half = tid&1 (key-dim half)
// each thread holds S[d in half*64..+64][col] in registers (64 floats)
__global__ __launch_bounds__(256) void recur_kernel(const float* __restrict__ Q,
                                                    const float* __restrict__ Kc,
                                                    const float* __restrict__ V,
                                                    const float* __restrict__ EG,
                                                    const float* __restrict__ BETA,
                                                    float* __restrict__ O,
                                                    int T)
{
    int bh = blockIdx.x;
    int b = bh / H, h = bh % H;
    int tid = threadIdx.x;
    int col = tid >> 1;
    int half = tid & 1;
    int dbase = half * 64;

    float S[64];
#pragma unroll
    for (int i = 0; i < 64; ++i) S[i] = 0.f;

    __shared__ __align__(16) float ks[2][128];
    __shared__ __align__(16) float qs[2][128];
    __shared__ __align__(16) float egs[2][128];
    __shared__ __align__(16) float vs[2][128];
    __shared__ float bs[2];

    size_t strideT = (size_t)H * D;
    size_t base0 = ((size_t)b * T * H + h) * D;
    const float* Qb = Q + base0;
    const float* Kb = Kc + base0;
    const float* Vb = V + base0;
    const float* Gb = EG + base0;
    const float* Bb = BETA + (size_t)b * T * H + h;
    float* Ob = O + base0;

    // prologue: stage t=0 into buffer 0
    if (tid < 128) {
        ks[0][tid] = Kb[tid];
        qs[0][tid] = Qb[tid];
    } else {
        int d2 = tid - 128;
        egs[0][d2] = Gb[d2];
        vs[0][d2] = Vb[d2];
    }
    if (tid == 0) bs[0] = Bb[0];

    int p = 0;
    for (int t = 0; t < T; ++t) {
        __syncthreads();
        // stage t+1 into the other buffer (no extra barrier needed)
        if (t + 1 < T) {
            size_t off = (size_t)(t + 1) * strideT;
            if (tid < 128) {
                ks[p ^ 1][tid] = Kb[off + tid];
                qs[p ^ 1][tid] = Qb[off + tid];
            } else {
                int d2 = tid - 128;
                egs[p ^ 1][d2] = Gb[off + d2];
                vs[p ^ 1][d2] = Vb[off + d2];
            }
            if (tid == 0) bs[p ^ 1] = Bb[(size_t)(t + 1) * H];
        }
        // compute on buffer p
        const float4* eg4 = (const float4*)&egs[p][dbase];
        const float4* k4p = (const float4*)&ks[p][dbase];
        const float4* q4p = (const float4*)&qs[p][dbase];
        float kv = 0.f;
#pragma unroll
        for (int g = 0; g < 16; ++g) {
            float4 e = eg4[g];
            float4 kk = k4p[g];
            float s0 = S[g * 4 + 0] * e.x;
            float s1 = S[g * 4 + 1] * e.y;
            float s2 = S[g * 4 + 2] * e.z;
            float s3 = S[g * 4 + 3] * e.w;
            kv += kk.x * s0 + kk.y * s1 + kk.z * s2 + kk.w * s3;
            S[g * 4 + 0] = s0; S[g * 4 + 1] = s1;
            S[g * 4 + 2] = s2; S[g * 4 + 3] = s3;
        }
        kv += __shfl_xor(kv, 1, 64);
        float delta = bs[p] * (vs[p][col] - kv);
        float oacc = 0.f;
#pragma unroll
        for (int g = 0; g < 16; ++g) {
            float4 kk = k4p[g];
            float4 qq = q4p[g];
            float s0 = S[g * 4 + 0] + kk.x * delta;
            float s1 = S[g * 4 + 1] + kk.y * delta;
            float s2 = S[g * 4 + 2] + kk.z * delta;
            float s3 = S[g * 4 + 3] + kk.w * delta;
            oacc += qq.x * s0 + qq.y * s1 + qq.z * s2 + qq.w * s3;
            S[g * 4 + 0] = s0; S[g * 4 + 1] = s1;
            S[g * 4 + 2] = s2; S[g * 4 + 3] = s3;
        }
        oacc += __shfl_xor(oacc, 1, 64);
        if (half == 0) Ob[(size_t)t * strideT + col] = oacc;
        p ^= 1;
    }
}

// ---------------- out = rmsnorm(o)*w*sigmoid(gate), in place on O ----------------
__global__ __launch_bounds__(128) void outnorm_kernel(float* __restrict__ O,
                                                      const float* __restrict__ GATE,
                                                      const float* __restrict__ w)
{
    int bid = blockIdx.x;            // (b*T + t)*H + h
    int d = threadIdx.x;
    size_t base = (size_t)bid * D;
    float y = O[base + d];
    __shared__ float red[2];
    float ss = y * y;
#pragma unroll
    for (int s = 32; s > 0; s >>= 1) ss += __shfl_xor(ss, s, 64);
    if ((threadIdx.x & 63) == 0) red[threadIdx.x >> 6] = ss;
    __syncthreads();
    float tot = red[0] + red[1];
    float r = rsqrtf(tot * (1.f / D) + 1e-5f);
    float gz = GATE[base + d];
    float sg = 1.f / (1.f + expf(-gz));
    O[base + d] = y * r * w[d] * sg;
}

extern "C" void kernel_launch(void* const* d_in, const int* in_sizes, int n_in,
                              void* d_out, int out_size, void* d_ws, size_t ws_size,
                              hipStream_t stream)
{
    const float* x       = (const float*)d_in[0];
    const float* Wq      = (const float*)d_in[1];
    const float* Wk      = (const float*)d_in[2];
    const float* Wv      = (const float*)d_in[3];
    const float* wq_conv = (const float*)d_in[4];
    const float* wk_conv = (const float*)d_in[5];
    const float* wv_conv = (const float*)d_in[6];
    const float* Wfa     = (const float*)d_in[7];
    const float* Wfb     = (const float*)d_in[8];
    const float* Wb      = (const float*)d_in[9];
    const float* Wga     = (const float*)d_in[10];
    const float* Wgb     = (const float*)d_in[11];
    const float* A_log   = (const float*)d_in[12];
    const float* dt_bias = (const float*)d_in[13];
    const float* o_norm_w= (const float*)d_in[14];
    const float* Wo      = (const float*)d_in[15];

    int BT = in_sizes[0] / HID;     // B*T
    int T = 1024;
    int B_ = BT / T;
    size_t M = (size_t)BT;
    size_t sz_big = M * HID;

    float* ws   = (float*)d_ws;
    float* Qp   = ws;
    float* Kp   = Qp + sz_big;
    float* Vp   = Kp + sz_big;
    float* Qc   = Vp + sz_big;
    float* Kc   = Qc + sz_big;
    float* Vc   = Kc + sz_big;
    float* XA   = Vc + sz_big;        // M*128
    float* XG   = XA + M * D;
    float* EGb  = XG + M * D;         // M*1024 (a_logits -> exp(g))
    float* GATE = EGb + sz_big;
    float* BETA = GATE + sz_big;      // M*H
    float* Obuf = BETA + M * H;       // M*1024

    dim3 blk(256);
    dim3 gBig(HID / 64, BT / 64);     // N=1024
    dim3 gSmall(D / 64, BT / 64);     // N=128

    // projections
    gemm_nt<<<gBig, blk, 0, stream>>>(x, Wq, Qp, BT, HID, HID);
    gemm_nt<<<gBig, blk, 0, stream>>>(x, Wk, Kp, BT, HID, HID);
    gemm_nt<<<gBig, blk, 0, stream>>>(x, Wv, Vp, BT, HID, HID);
    gemm_nt<<<gSmall, blk, 0, stream>>>(x, Wfa, XA, BT, D, HID);
    gemm_nt<<<gSmall, blk, 0, stream>>>(x, Wga, XG, BT, D, HID);
    beta_kernel<<<BT, 256, 0, stream>>>(x, Wb, BETA);

    // conv + silu (+norm)
    const float scale  = 0.08838834764831845f;   // D^-0.5
    const float scale2 = 1.0f / 128.0f;          // D^-1
    conv_kernel<<<BT * H, 128, 0, stream>>>(Qp, wq_conv, Qc, 1, scale2, T);
    conv_kernel<<<BT * H, 128, 0, stream>>>(Kp, wk_conv, Kc, 2, scale, T);
    conv_kernel<<<BT * H, 128, 0, stream>>>(Vp, wv_conv, Vc, 0, 1.f, T);

    // low-rank heads
    gemm_nt<<<gBig, blk, 0, stream>>>(XA, Wfb, EGb, BT, HID, D);
    gemm_nt<<<gBig, blk, 0, stream>>>(XG, Wgb, GATE, BT, HID, D);
    eg_kernel<<<(int)((M * HID + 255) / 256), 256, 0, stream>>>(EGb, A_log, dt_bias, (int)(M * HID));

    // recurrence
    recur_kernel<<<B_ * H, 256, 0, stream>>>(Qc, Kc, Vc, EGb, BETA, Obuf, T);

    // output norm * gate
    outnorm_kernel<<<BT * H, 128, 0, stream>>>(Obuf, GATE, o_norm_w);

    // final projection
    gemm_nt<<<gBig, blk, 0, stream>>>(Obuf, Wo, (float*)d_out, BT, HID, HID);
}

// Round 2
// 1172.397 us; speedup vs baseline: 2.3442x; 2.3442x over previous
//
#include <hip/hip_runtime.h>
#include <hip/hip_bf16.h>
#include <math.h>

#define H 8
#define D 128
#define HID 1024
#define KCONV 4

// ---------------- GEMM: C[M,N] = A[M,K] * B[N,K]^T ----------------
// 64x64 tile, BK=16, 256 threads, 4x4 per thread, fp32.
__global__ __launch_bounds__(256) void gemm_nt(const float* __restrict__ A,
                                               const float* __restrict__ B,
                                               float* __restrict__ C,
                                               int M, int N, int K)
{
    __shared__ __align__(16) float As[16][68];
    __shared__ __align__(16) float Bs[16][68];
    int tid = threadIdx.x;
    int tx = tid % 16;
    int ty = tid / 16;
    int rowBase = blockIdx.y * 64;
    int colBase = blockIdx.x * 64;
    int lk = tid % 16;   // k offset within BK
    int lr = tid / 16;   // row 0..15 (+16 per rep)
    float acc[4][4] = {};

    for (int k0 = 0; k0 < K; k0 += 16) {
#pragma unroll
        for (int rep = 0; rep < 4; ++rep) {
            int r = lr + rep * 16;
            As[lk][r] = A[(size_t)(rowBase + r) * K + k0 + lk];
            Bs[lk][r] = B[(size_t)(colBase + r) * K + k0 + lk];
        }
        __syncthreads();
#pragma unroll
        for (int kk = 0; kk < 16; ++kk) {
            float4 a4 = *(const float4*)&As[kk][ty * 4];
            float4 b4 = *(const float4*)&Bs[kk][tx * 4];
            float av[4] = {a4.x, a4.y, a4.z, a4.w};
            float bv[4] = {b4.x, b4.y, b4.z, b4.w};
#pragma unroll
            for (int i = 0; i < 4; ++i)
#pragma unroll
                for (int j = 0; j < 4; ++j)
                    acc[i][j] += av[i] * bv[j];
        }
        __syncthreads();
    }
#pragma unroll
    for (int i = 0; i < 4; ++i) {
        float4 o = make_float4(acc[i][0], acc[i][1], acc[i][2], acc[i][3]);
        *(float4*)&C[(size_t)(rowBase + ty * 4 + i) * N + colBase + tx * 4] = o;
    }
}

// ---------------- beta = sigmoid(x @ Wb^T), Wb: (H, HID) ----------------
__global__ __launch_bounds__(256) void beta_kernel(const float* __restrict__ x,
                                                   const float* __restrict__ Wb,
                                                   float* __restrict__ beta)
{
    int row = blockIdx.x;            // b*T + t
    int tid = threadIdx.x;
    int h = tid >> 5;                // 8 heads x 32 lanes
    int lane = tid & 31;
    const float* xr = x + (size_t)row * HID;
    const float* wr = Wb + (size_t)h * HID;
    float acc = 0.f;
    for (int k = lane; k < HID; k += 32) acc += xr[k] * wr[k];
#pragma unroll
    for (int s = 16; s > 0; s >>= 1) acc += __shfl_xor(acc, s, 64);
    if (lane == 0) beta[(size_t)row * H + h] = 1.f / (1.f + expf(-acc));
}

// ---------------- depthwise causal conv (K=4) + SiLU (+ rmsnorm*scale) ----------------
// mode 0: v (silu only); mode 1/2: q/k (silu + rmsnorm + scale)
__global__ __launch_bounds__(128) void conv_kernel(const float* __restrict__ P,
                                                   const float* __restrict__ w,
                                                   float* __restrict__ out,
                                                   int mode, float scale, int T)
{
    int bid = blockIdx.x;            // (b*T + t)*H + h
    int h = bid % H;
    int t = (bid / H) % T;
    int b = bid / (H * T);
    int d = threadIdx.x;
    int c = h * D + d;
    const float* base = P + (size_t)b * T * HID;
    float acc = 0.f;
#pragma unroll
    for (int j = 0; j < KCONV; ++j) {
        int tt = t - (KCONV - 1) + j;
        float xv = (tt >= 0) ? base[(size_t)tt * HID + c] : 0.f;
        acc += xv * w[c * KCONV + j];
    }
    float y = acc / (1.f + expf(-acc));   // SiLU
    if (mode) {
        __shared__ float red[2];
        float ss = y * y;
#pragma unroll
        for (int s = 32; s > 0; s >>= 1) ss += __shfl_xor(ss, s, 64);
        if ((threadIdx.x & 63) == 0) red[threadIdx.x >> 6] = ss;
        __syncthreads();
        float tot = red[0] + red[1];
        float r = rsqrtf(tot * (1.f / D) + 1e-6f);
        y = y * r * scale;
    }
    out[(size_t)bid * D + d] = y;
}

// ---------------- a_logits -> exp(g) in place ----------------
__global__ void eg_kernel(float* __restrict__ a, const float* __restrict__ A_log,
                          const float* __restrict__ dt_bias, int n)
{
    int i = blockIdx.x * blockDim.x + threadIdx.x;
    if (i >= n) return;
    int d = i % D;
    int h = (i / D) % H;
    float z = a[i] + dt_bias[h * D + d];
    float sp = (z > 20.f) ? z : log1pf(expf(z));
    a[i] = expf(-expf(A_log[h]) * sp);
}

// ---------------- gated delta-rule recurrence, column-parallel ----------------
// One wave per (b, h, value-column): 2048 independent waves, zero barriers,
// zero LDS. Each lane owns S[2*lane .. 2*lane+1][col]; Dk-reductions via
// 6-level shfl_xor butterfly. k/q/eg/v/beta for step t+1 are prefetched into
// registers while step t computes (hides ~200cyc L2 latency under the chain).
__global__ __launch_bounds__(256) void recur_cols_kernel(const float* __restrict__ Q,
                                                         const float* __restrict__ Kc,
                                                         const float* __restrict__ V,
                                                         const float* __restrict__ EG,
                                                         const float* __restrict__ BETA,
                                                         float* __restrict__ O,
                                                         int T)
{
    int gw = blockIdx.x * 4 + (threadIdx.x >> 6);   // global wave id
    int lane = threadIdx.x & 63;
    int bh = gw >> 7;            // 128 columns per (b,h)
    int col = gw & 127;
    int b = bh >> 3, h = bh & 7;

    size_t base = ((size_t)b * T * H + h) * D;
    const float* Kb = Kc + base;
    const float* Qb = Q + base;
    const float* Gb = EG + base;
    const float* Vb = V + base + col;
    const float* Bb = BETA + (size_t)b * T * H + h;
    float* Ob = O + base + col;

    int d0 = lane * 2;
    float S0 = 0.f, S1 = 0.f;

    const int strideT = H * D;   // 1024

    // prefetch t=0
    float2 kk = *(const float2*)(Kb + d0);
    float2 qq = *(const float2*)(Qb + d0);
    float2 ee = *(const float2*)(Gb + d0);
    float vv = *Vb;
    float bb = *Bb;

    for (int t = 0; t < T; ++t) {
        float2 kc = kk, qc = qq, ec = ee;
        float vc = vv, bc = bb;
        if (t + 1 < T) {
            size_t off = (size_t)(t + 1) * strideT;
            kk = *(const float2*)(Kb + off + d0);
            qq = *(const float2*)(Qb + off + d0);
            ee = *(const float2*)(Gb + off + d0);
            vv = Vb[off];
            bb = Bb[(size_t)(t + 1) * H];
        }
        // decay + read
        S0 *= ec.x;
        S1 *= ec.y;
        float kv = kc.x * S0 + kc.y * S1;
#pragma unroll
        for (int s = 1; s < 64; s <<= 1) kv += __shfl_xor(kv, s, 64);
        float delta = bc * (vc - kv);
        // rank-1 write + output read
        S0 += kc.x * delta;
        S1 += kc.y * delta;
        float o = qc.x * S0 + qc.y * S1;
#pragma unroll
        for (int s = 1; s < 64; s <<= 1) o += __shfl_xor(o, s, 64);
        if (lane == 0) Ob[(size_t)t * strideT] = o;
    }
}

// ---------------- out = rmsnorm(o)*w*sigmoid(gate), in place on O ----------------
__global__ __launch_bounds__(128) void outnorm_kernel(float* __restrict__ O,
                                                      const float* __restrict__ GATE,
                                                      const float* __restrict__ w)
{
    int bid = blockIdx.x;            // (b*T + t)*H + h
    int d = threadIdx.x;
    size_t base = (size_t)bid * D;
    float y = O[base + d];
    __shared__ float red[2];
    float ss = y * y;
#pragma unroll
    for (int s = 32; s > 0; s >>= 1) ss += __shfl_xor(ss, s, 64);
    if ((threadIdx.x & 63) == 0) red[threadIdx.x >> 6] = ss;
    __syncthreads();
    float tot = red[0] + red[1];
    float r = rsqrtf(tot * (1.f / D) + 1e-5f);
    float gz = GATE[base + d];
    float sg = 1.f / (1.f + expf(-gz));
    O[base + d] = y * r * w[d] * sg;
}

extern "C" void kernel_launch(void* const* d_in, const int* in_sizes, int n_in,
                              void* d_out, int out_size, void* d_ws, size_t ws_size,
                              hipStream_t stream)
{
    const float* x       = (const float*)d_in[0];
    const float* Wq      = (const float*)d_in[1];
    const float* Wk      = (const float*)d_in[2];
    const float* Wv      = (const float*)d_in[3];
    const float* wq_conv = (const float*)d_in[4];
    const float* wk_conv = (const float*)d_in[5];
    const float* wv_conv = (const float*)d_in[6];
    const float* Wfa     = (const float*)d_in[7];
    const float* Wfb     = (const float*)d_in[8];
    const float* Wb      = (const float*)d_in[9];
    const float* Wga     = (const float*)d_in[10];
    const float* Wgb     = (const float*)d_in[11];
    const float* A_log   = (const float*)d_in[12];
    const float* dt_bias = (const float*)d_in[13];
    const float* o_norm_w= (const float*)d_in[14];
    const float* Wo      = (const float*)d_in[15];

    int BT = in_sizes[0] / HID;     // B*T
    int T = 1024;
    int B_ = BT / T;
    size_t M = (size_t)BT;
    size_t sz_big = M * HID;

    float* ws   = (float*)d_ws;
    float* Qp   = ws;
    float* Kp   = Qp + sz_big;
    float* Vp   = Kp + sz_big;
    float* Qc   = Vp + sz_big;
    float* Kc   = Qc + sz_big;
    float* Vc   = Kc + sz_big;
    float* XA   = Vc + sz_big;        // M*128
    float* XG   = XA + M * D;
    float* EGb  = XG + M * D;         // M*1024 (a_logits -> exp(g))
    float* GATE = EGb + sz_big;
    float* BETA = GATE + sz_big;      // M*H
    float* Obuf = BETA + M * H;       // M*1024

    dim3 blk(256);
    dim3 gBig(HID / 64, BT / 64);     // N=1024
    dim3 gSmall(D / 64, BT / 64);     // N=128

    // projections
    gemm_nt<<<gBig, blk, 0, stream>>>(x, Wq, Qp, BT, HID, HID);
    gemm_nt<<<gBig, blk, 0, stream>>>(x, Wk, Kp, BT, HID, HID);
    gemm_nt<<<gBig, blk, 0, stream>>>(x, Wv, Vp, BT, HID, HID);
    gemm_nt<<<gSmall, blk, 0, stream>>>(x, Wfa, XA, BT, D, HID);
    gemm_nt<<<gSmall, blk, 0, stream>>>(x, Wga, XG, BT, D, HID);
    beta_kernel<<<BT, 256, 0, stream>>>(x, Wb, BETA);

    // conv + silu (+norm)
    const float scale  = 0.08838834764831845f;   // D^-0.5
    const float scale2 = 1.0f / 128.0f;          // D^-1
    conv_kernel<<<BT * H, 128, 0, stream>>>(Qp, wq_conv, Qc, 1, scale2, T);
    conv_kernel<<<BT * H, 128, 0, stream>>>(Kp, wk_conv, Kc, 2, scale, T);
    conv_kernel<<<BT * H, 128, 0, stream>>>(Vp, wv_conv, Vc, 0, 1.f, T);

    // low-rank heads
    gemm_nt<<<gBig, blk, 0, stream>>>(XA, Wfb, EGb, BT, HID, D);
    gemm_nt<<<gBig, blk, 0, stream>>>(XG, Wgb, GATE, BT, HID, D);
    eg_kernel<<<(int)((M * HID + 255) / 256), 256, 0, stream>>>(EGb, A_log, dt_bias, (int)(M * HID));

    // recurrence: one wave per (b,h,col) -> B*H*128 waves, 4 waves/block
    recur_cols_kernel<<<B_ * H * 32, 256, 0, stream>>>(Qc, Kc, Vc, EGb, BETA, Obuf, T);

    // output norm * gate
    outnorm_kernel<<<BT * H, 128, 0, stream>>>(Obuf, GATE, o_norm_w);

    // final projection
    gemm_nt<<<gBig, blk, 0, stream>>>(Obuf, Wo, (float*)d_out, BT, HID, HID);
}

// Round 3
// 1122.536 us; speedup vs baseline: 2.4483x; 1.0444x over previous
//
#include <hip/hip_runtime.h>
#include <hip/hip_bf16.h>
#include <math.h>

#define H 8
#define D 128
#define HID 1024
#define KCONV 4
#define PF 4   // prefetch depth in recurrence

// ---------------- GEMM: C[M,N] = A[M,K] * B[N,K]^T ----------------
// 64x64 tile, BK=16, 256 threads, 4x4 per thread, fp32.
__global__ __launch_bounds__(256) void gemm_nt(const float* __restrict__ A,
                                               const float* __restrict__ B,
                                               float* __restrict__ C,
                                               int M, int N, int K)
{
    __shared__ __align__(16) float As[16][68];
    __shared__ __align__(16) float Bs[16][68];
    int tid = threadIdx.x;
    int tx = tid % 16;
    int ty = tid / 16;
    int rowBase = blockIdx.y * 64;
    int colBase = blockIdx.x * 64;
    int lk = tid % 16;   // k offset within BK
    int lr = tid / 16;   // row 0..15 (+16 per rep)
    float acc[4][4] = {};

    for (int k0 = 0; k0 < K; k0 += 16) {
#pragma unroll
        for (int rep = 0; rep < 4; ++rep) {
            int r = lr + rep * 16;
            As[lk][r] = A[(size_t)(rowBase + r) * K + k0 + lk];
            Bs[lk][r] = B[(size_t)(colBase + r) * K + k0 + lk];
        }
        __syncthreads();
#pragma unroll
        for (int kk = 0; kk < 16; ++kk) {
            float4 a4 = *(const float4*)&As[kk][ty * 4];
            float4 b4 = *(const float4*)&Bs[kk][tx * 4];
            float av[4] = {a4.x, a4.y, a4.z, a4.w};
            float bv[4] = {b4.x, b4.y, b4.z, b4.w};
#pragma unroll
            for (int i = 0; i < 4; ++i)
#pragma unroll
                for (int j = 0; j < 4; ++j)
                    acc[i][j] += av[i] * bv[j];
        }
        __syncthreads();
    }
#pragma unroll
    for (int i = 0; i < 4; ++i) {
        float4 o = make_float4(acc[i][0], acc[i][1], acc[i][2], acc[i][3]);
        *(float4*)&C[(size_t)(rowBase + ty * 4 + i) * N + colBase + tx * 4] = o;
    }
}

// ---------------- beta = sigmoid(x @ Wb^T), Wb: (H, HID) ----------------
__global__ __launch_bounds__(256) void beta_kernel(const float* __restrict__ x,
                                                   const float* __restrict__ Wb,
                                                   float* __restrict__ beta)
{
    int row = blockIdx.x;            // b*T + t
    int tid = threadIdx.x;
    int h = tid >> 5;                // 8 heads x 32 lanes
    int lane = tid & 31;
    const float* xr = x + (size_t)row * HID;
    const float* wr = Wb + (size_t)h * HID;
    float acc = 0.f;
    for (int k = lane; k < HID; k += 32) acc += xr[k] * wr[k];
#pragma unroll
    for (int s = 16; s > 0; s >>= 1) acc += __shfl_xor(acc, s, 64);
    if (lane == 0) beta[(size_t)row * H + h] = 1.f / (1.f + expf(-acc));
}

// ---------------- depthwise causal conv (K=4) + SiLU (+ rmsnorm*scale) ----------------
// mode 0: v (silu only); mode 1/2: q/k (silu + rmsnorm + scale)
__global__ __launch_bounds__(128) void conv_kernel(const float* __restrict__ P,
                                                   const float* __restrict__ w,
                                                   float* __restrict__ out,
                                                   int mode, float scale, int T)
{
    int bid = blockIdx.x;            // (b*T + t)*H + h
    int h = bid % H;
    int t = (bid / H) % T;
    int b = bid / (H * T);
    int d = threadIdx.x;
    int c = h * D + d;
    const float* base = P + (size_t)b * T * HID;
    float acc = 0.f;
#pragma unroll
    for (int j = 0; j < KCONV; ++j) {
        int tt = t - (KCONV - 1) + j;
        float xv = (tt >= 0) ? base[(size_t)tt * HID + c] : 0.f;
        acc += xv * w[c * KCONV + j];
    }
    float y = acc / (1.f + expf(-acc));   // SiLU
    if (mode) {
        __shared__ float red[2];
        float ss = y * y;
#pragma unroll
        for (int s = 32; s > 0; s >>= 1) ss += __shfl_xor(ss, s, 64);
        if ((threadIdx.x & 63) == 0) red[threadIdx.x >> 6] = ss;
        __syncthreads();
        float tot = red[0] + red[1];
        float r = rsqrtf(tot * (1.f / D) + 1e-6f);
        y = y * r * scale;
    }
    out[(size_t)bid * D + d] = y;
}

// ---------------- a_logits -> exp(g) in place ----------------
__global__ void eg_kernel(float* __restrict__ a, const float* __restrict__ A_log,
                          const float* __restrict__ dt_bias, int n)
{
    int i = blockIdx.x * blockDim.x + threadIdx.x;
    if (i >= n) return;
    int d = i % D;
    int h = (i / D) % H;
    float z = a[i] + dt_bias[h * D + d];
    float sp = (z > 20.f) ? z : log1pf(expf(z));
    a[i] = expf(-expf(A_log[h]) * sp);
}

// ---------------- DPP wave64 reduction: sum of all lanes -> uniform scalar ----
// row_shr 1/2/4/8 + row_bcast:15 + row_bcast:31 -> total in lane 63, readlane.
template <int CTRL>
__device__ __forceinline__ float dpp_add(float x) {
    int y = __builtin_amdgcn_update_dpp(0, __builtin_bit_cast(int, x),
                                        CTRL, 0xF, 0xF, false);
    return x + __builtin_bit_cast(float, y);
}
__device__ __forceinline__ float wave_sum(float x) {
    x = dpp_add<0x111>(x);   // row_shr:1
    x = dpp_add<0x112>(x);   // row_shr:2
    x = dpp_add<0x114>(x);   // row_shr:4
    x = dpp_add<0x118>(x);   // row_shr:8
    x = dpp_add<0x142>(x);   // row_bcast:15
    x = dpp_add<0x143>(x);   // row_bcast:31
    return __builtin_bit_cast(float,
        __builtin_amdgcn_readlane(__builtin_bit_cast(int, x), 63));
}

// ---------------- gated delta-rule recurrence, column-parallel ----------------
// One wave per (b, h, value-column): 2048 independent waves, zero barriers,
// zero LDS. Lane owns S[2*lane..2*lane+1][col]. Three concurrent DPP
// reductions per step (k·S', q·S', q·k); o = q·S' + (q·k)·delta keeps the
// output reduction off the S-update critical path. Register ring buffer
// prefetches k/q/eg/v/beta PF steps ahead.
__global__ __launch_bounds__(256) void recur_cols_kernel(const float* __restrict__ Q,
                                                         const float* __restrict__ Kc,
                                                         const float* __restrict__ V,
                                                         const float* __restrict__ EG,
                                                         const float* __restrict__ BETA,
                                                         float* __restrict__ O,
                                                         int T)
{
    int gw = blockIdx.x * 4 + (threadIdx.x >> 6);   // global wave id
    int lane = threadIdx.x & 63;
    int bh = gw >> 7;            // 128 columns per (b,h)
    int col = gw & 127;
    int b = bh >> 3, h = bh & 7;

    size_t base = ((size_t)b * T * H + h) * D;
    const float* Kb = Kc + base;
    const float* Qb = Q + base;
    const float* Gb = EG + base;
    const float* Vb = V + base + col;
    const float* Bb = BETA + (size_t)b * T * H + h;
    float* Ob = O + base + col;

    int d0 = lane * 2;
    float S0 = 0.f, S1 = 0.f;

    const int strideT = H * D;   // 1024

    float2 kbuf[PF], qbuf[PF], ebuf[PF];
    float vbuf[PF], bbuf[PF];
#pragma unroll
    for (int i = 0; i < PF; ++i) {
        size_t off = (size_t)i * strideT;
        kbuf[i] = *(const float2*)(Kb + off + d0);
        qbuf[i] = *(const float2*)(Qb + off + d0);
        ebuf[i] = *(const float2*)(Gb + off + d0);
        vbuf[i] = Vb[off];
        bbuf[i] = Bb[(size_t)i * H];
    }

    for (int t4 = 0; t4 < T; t4 += PF) {
#pragma unroll
        for (int i = 0; i < PF; ++i) {
            int t = t4 + i;
            float2 kc = kbuf[i], qc = qbuf[i], ec = ebuf[i];
            float vc = vbuf[i], bc = bbuf[i];
            if (t + PF < T) {
                size_t off = (size_t)(t + PF) * strideT;
                kbuf[i] = *(const float2*)(Kb + off + d0);
                qbuf[i] = *(const float2*)(Qb + off + d0);
                ebuf[i] = *(const float2*)(Gb + off + d0);
                vbuf[i] = Vb[off];
                bbuf[i] = Bb[(size_t)(t + PF) * H];
            }
            // decay
            S0 *= ec.x;
            S1 *= ec.y;
            // three independent reductions (only R1 is on the critical path)
            float R1 = wave_sum(kc.x * S0 + kc.y * S1);       // k . S'
            float R2 = wave_sum(qc.x * S0 + qc.y * S1);       // q . S'
            float R3 = wave_sum(kc.x * qc.x + kc.y * qc.y);   // q . k
            float delta = bc * (vc - R1);
            S0 += kc.x * delta;
            S1 += kc.y * delta;
            if (lane == 0) Ob[(size_t)t * strideT] = R2 + R3 * delta;
        }
    }
}

// ---------------- out = rmsnorm(o)*w*sigmoid(gate), in place on O ----------------
__global__ __launch_bounds__(128) void outnorm_kernel(float* __restrict__ O,
                                                      const float* __restrict__ GATE,
                                                      const float* __restrict__ w)
{
    int bid = blockIdx.x;            // (b*T + t)*H + h
    int d = threadIdx.x;
    size_t base = (size_t)bid * D;
    float y = O[base + d];
    __shared__ float red[2];
    float ss = y * y;
#pragma unroll
    for (int s = 32; s > 0; s >>= 1) ss += __shfl_xor(ss, s, 64);
    if ((threadIdx.x & 63) == 0) red[threadIdx.x >> 6] = ss;
    __syncthreads();
    float tot = red[0] + red[1];
    float r = rsqrtf(tot * (1.f / D) + 1e-5f);
    float gz = GATE[base + d];
    float sg = 1.f / (1.f + expf(-gz));
    O[base + d] = y * r * w[d] * sg;
}

extern "C" void kernel_launch(void* const* d_in, const int* in_sizes, int n_in,
                              void* d_out, int out_size, void* d_ws, size_t ws_size,
                              hipStream_t stream)
{
    const float* x       = (const float*)d_in[0];
    const float* Wq      = (const float*)d_in[1];
    const float* Wk      = (const float*)d_in[2];
    const float* Wv      = (const float*)d_in[3];
    const float* wq_conv = (const float*)d_in[4];
    const float* wk_conv = (const float*)d_in[5];
    const float* wv_conv = (const float*)d_in[6];
    const float* Wfa     = (const float*)d_in[7];
    const float* Wfb     = (const float*)d_in[8];
    const float* Wb      = (const float*)d_in[9];
    const float* Wga     = (const float*)d_in[10];
    const float* Wgb     = (const float*)d_in[11];
    const float* A_log   = (const float*)d_in[12];
    const float* dt_bias = (const float*)d_in[13];
    const float* o_norm_w= (const float*)d_in[14];
    const float* Wo      = (const float*)d_in[15];

    int BT = in_sizes[0] / HID;     // B*T
    int T = 1024;
    int B_ = BT / T;
    size_t M = (size_t)BT;
    size_t sz_big = M * HID;

    float* ws   = (float*)d_ws;
    float* Qp   = ws;
    float* Kp   = Qp + sz_big;
    float* Vp   = Kp + sz_big;
    float* Qc   = Vp + sz_big;
    float* Kc   = Qc + sz_big;
    float* Vc   = Kc + sz_big;
    float* XA   = Vc + sz_big;        // M*128
    float* XG   = XA + M * D;
    float* EGb  = XG + M * D;         // M*1024 (a_logits -> exp(g))
    float* GATE = EGb + sz_big;
    float* BETA = GATE + sz_big;      // M*H
    float* Obuf = BETA + M * H;       // M*1024

    dim3 blk(256);
    dim3 gBig(HID / 64, BT / 64);     // N=1024
    dim3 gSmall(D / 64, BT / 64);     // N=128

    // projections
    gemm_nt<<<gBig, blk, 0, stream>>>(x, Wq, Qp, BT, HID, HID);
    gemm_nt<<<gBig, blk, 0, stream>>>(x, Wk, Kp, BT, HID, HID);
    gemm_nt<<<gBig, blk, 0, stream>>>(x, Wv, Vp, BT, HID, HID);
    gemm_nt<<<gSmall, blk, 0, stream>>>(x, Wfa, XA, BT, D, HID);
    gemm_nt<<<gSmall, blk, 0, stream>>>(x, Wga, XG, BT, D, HID);
    beta_kernel<<<BT, 256, 0, stream>>>(x, Wb, BETA);

    // conv + silu (+norm)
    const float scale  = 0.08838834764831845f;   // D^-0.5
    const float scale2 = 1.0f / 128.0f;          // D^-1
    conv_kernel<<<BT * H, 128, 0, stream>>>(Qp, wq_conv, Qc, 1, scale2, T);
    conv_kernel<<<BT * H, 128, 0, stream>>>(Kp, wk_conv, Kc, 2, scale, T);
    conv_kernel<<<BT * H, 128, 0, stream>>>(Vp, wv_conv, Vc, 0, 1.f, T);

    // low-rank heads
    gemm_nt<<<gBig, blk, 0, stream>>>(XA, Wfb, EGb, BT, HID, D);
    gemm_nt<<<gBig, blk, 0, stream>>>(XG, Wgb, GATE, BT, HID, D);
    eg_kernel<<<(int)((M * HID + 255) / 256), 256, 0, stream>>>(EGb, A_log, dt_bias, (int)(M * HID));

    // recurrence: one wave per (b,h,col) -> B*H*128 waves, 4 waves/block
    recur_cols_kernel<<<B_ * H * 32, 256, 0, stream>>>(Qc, Kc, Vc, EGb, BETA, Obuf, T);

    // output norm * gate
    outnorm_kernel<<<BT * H, 128, 0, stream>>>(Obuf, GATE, o_norm_w);

    // final projection
    gemm_nt<<<gBig, blk, 0, stream>>>(Obuf, Wo, (float*)d_out, BT, HID, HID);
}

// Round 4
// 614.941 us; speedup vs baseline: 4.4692x; 1.8254x over previous
//
#include <hip/hip_runtime.h>
#include <hip/hip_bf16.h>
#include <math.h>

#define H 8
#define D 128
#define HID 1024
#define KCONV 4
#define G 8            // recurrence: steps per LDS group

typedef __bf16 bhalf;
typedef __bf16 bhalf8 __attribute__((ext_vector_type(8)));
typedef float f32x4 __attribute__((ext_vector_type(4)));

// ---- async global->LDS (direct-to-shared DMA, bypasses VGPRs) ----
__device__ __forceinline__ void async16(const void* g, void* l) {
    __builtin_amdgcn_global_load_lds(
        (const __attribute__((address_space(1))) void*)g,
        (__attribute__((address_space(3))) void*)l, 16, 0, 0);
}
__device__ __forceinline__ void async4(const void* g, void* l) {
    __builtin_amdgcn_global_load_lds(
        (const __attribute__((address_space(1))) void*)g,
        (__attribute__((address_space(3))) void*)l, 4, 0, 0);
}

// ---------------- fp32 GEMM (small/decay-path): C[M,N] = A[M,K]*B[N,K]^T ----
__global__ __launch_bounds__(256) void gemm_nt(const float* __restrict__ A,
                                               const float* __restrict__ B,
                                               float* __restrict__ C,
                                               int M, int N, int K)
{
    __shared__ __align__(16) float As[16][68];
    __shared__ __align__(16) float Bs[16][68];
    int tid = threadIdx.x;
    int tx = tid % 16;
    int ty = tid / 16;
    int rowBase = blockIdx.y * 64;
    int colBase = blockIdx.x * 64;
    int lk = tid % 16;
    int lr = tid / 16;
    float acc[4][4] = {};

    for (int k0 = 0; k0 < K; k0 += 16) {
#pragma unroll
        for (int rep = 0; rep < 4; ++rep) {
            int r = lr + rep * 16;
            As[lk][r] = A[(size_t)(rowBase + r) * K + k0 + lk];
            Bs[lk][r] = B[(size_t)(colBase + r) * K + k0 + lk];
        }
        __syncthreads();
#pragma unroll
        for (int kk = 0; kk < 16; ++kk) {
            float4 a4 = *(const float4*)&As[kk][ty * 4];
            float4 b4 = *(const float4*)&Bs[kk][tx * 4];
            float av[4] = {a4.x, a4.y, a4.z, a4.w};
            float bv[4] = {b4.x, b4.y, b4.z, b4.w};
#pragma unroll
            for (int i = 0; i < 4; ++i)
#pragma unroll
                for (int j = 0; j < 4; ++j)
                    acc[i][j] += av[i] * bv[j];
        }
        __syncthreads();
    }
#pragma unroll
    for (int i = 0; i < 4; ++i) {
        float4 o = make_float4(acc[i][0], acc[i][1], acc[i][2], acc[i][3]);
        *(float4*)&C[(size_t)(rowBase + ty * 4 + i) * N + colBase + tx * 4] = o;
    }
}

// ---------------- bf16 MFMA GEMM: C[M,N](fp32) = A[M,K]*B[N,K]^T, bf16 in ----
// 128x64 tile, BK=32, 256 threads (4 waves, 2x2), global_load_lds staging.
__global__ __launch_bounds__(256) void gemm_bf16_nt(const bhalf* __restrict__ A,
                                                    const bhalf* __restrict__ B,
                                                    float* __restrict__ C,
                                                    int M, int N, int K)
{
    __shared__ __align__(16) bhalf As[128][32];   // 8 KB
    __shared__ __align__(16) bhalf Bs[64][32];    // 4 KB
    int tid = threadIdx.x;
    int wid = tid >> 6, lane = tid & 63;
    int rowBase = blockIdx.y * 128;
    int colBase = blockIdx.x * 64;
    int wm = wid >> 1, wn = wid & 1;

    f32x4 acc[4][2] = {};

    int r = lane >> 2;          // 16 rows per 1KB instr
    int cseg = lane & 3;        // 16B segment within 64B row

    for (int k0 = 0; k0 < K; k0 += 32) {
        __syncthreads();
#pragma unroll
        for (int s = 0; s < 3; ++s) {
            int j = wid * 3 + s;            // 12 instrs: 8 A + 4 B
            if (j < 8) {
                const bhalf* ga = A + (size_t)(rowBase + j * 16 + r) * K + k0 + cseg * 8;
                async16(ga, &As[j * 16][0]);
            } else {
                int jb = j - 8;
                const bhalf* ga = B + (size_t)(colBase + jb * 16 + r) * K + k0 + cseg * 8;
                async16(ga, &Bs[jb * 16][0]);
            }
        }
        __syncthreads();
        int mq = lane & 15, kq = (lane >> 4) * 8;
        bhalf8 a[4], bfr[2];
#pragma unroll
        for (int mt = 0; mt < 4; ++mt)
            a[mt] = *(const bhalf8*)&As[wm * 64 + mt * 16 + mq][kq];
#pragma unroll
        for (int nt = 0; nt < 2; ++nt)
            bfr[nt] = *(const bhalf8*)&Bs[wn * 32 + nt * 16 + mq][kq];
#pragma unroll
        for (int mt = 0; mt < 4; ++mt)
#pragma unroll
            for (int nt = 0; nt < 2; ++nt)
                acc[mt][nt] = __builtin_amdgcn_mfma_f32_16x16x32_bf16(
                    a[mt], bfr[nt], acc[mt][nt], 0, 0, 0);
    }
    int n0 = colBase + wn * 32 + (lane & 15);
    int rquad = (lane >> 4) * 4;
#pragma unroll
    for (int mt = 0; mt < 4; ++mt) {
        int m0 = rowBase + wm * 64 + mt * 16 + rquad;
#pragma unroll
        for (int nt = 0; nt < 2; ++nt)
#pragma unroll
            for (int rr = 0; rr < 4; ++rr)
                C[(size_t)(m0 + rr) * N + n0 + nt * 16] = acc[mt][nt][rr];
    }
}

// ---------------- cast fp32 -> bf16 ----------------
__global__ void cast_bf16(const float* __restrict__ in, bhalf* __restrict__ out, int n)
{
    int i = blockIdx.x * blockDim.x + threadIdx.x;
    if (i < n) out[i] = (bhalf)in[i];
}

// ---------------- beta = sigmoid(x @ Wb^T), Wb: (H, HID) ----------------
__global__ __launch_bounds__(256) void beta_kernel(const float* __restrict__ x,
                                                   const float* __restrict__ Wb,
                                                   float* __restrict__ beta)
{
    int row = blockIdx.x;
    int tid = threadIdx.x;
    int h = tid >> 5;
    int lane = tid & 31;
    const float* xr = x + (size_t)row * HID;
    const float* wr = Wb + (size_t)h * HID;
    float acc = 0.f;
    for (int k = lane; k < HID; k += 32) acc += xr[k] * wr[k];
#pragma unroll
    for (int s = 16; s > 0; s >>= 1) acc += __shfl_xor(acc, s, 64);
    if (lane == 0) beta[(size_t)row * H + h] = 1.f / (1.f + expf(-acc));
}

// ---------------- depthwise causal conv (K=4) + SiLU (+ rmsnorm*scale) ------
__global__ __launch_bounds__(128) void conv_kernel(const float* __restrict__ P,
                                                   const float* __restrict__ w,
                                                   float* __restrict__ out,
                                                   int mode, float scale, int T)
{
    int bid = blockIdx.x;
    int h = bid % H;
    int t = (bid / H) % T;
    int b = bid / (H * T);
    int d = threadIdx.x;
    int c = h * D + d;
    const float* base = P + (size_t)b * T * HID;
    float acc = 0.f;
#pragma unroll
    for (int j = 0; j < KCONV; ++j) {
        int tt = t - (KCONV - 1) + j;
        float xv = (tt >= 0) ? base[(size_t)tt * HID + c] : 0.f;
        acc += xv * w[c * KCONV + j];
    }
    float y = acc / (1.f + expf(-acc));
    if (mode) {
        __shared__ float red[2];
        float ss = y * y;
#pragma unroll
        for (int s = 32; s > 0; s >>= 1) ss += __shfl_xor(ss, s, 64);
        if ((threadIdx.x & 63) == 0) red[threadIdx.x >> 6] = ss;
        __syncthreads();
        float tot = red[0] + red[1];
        float r = rsqrtf(tot * (1.f / D) + 1e-6f);
        y = y * r * scale;
    }
    out[(size_t)bid * D + d] = y;
}

// ---------------- a_logits -> exp(g) in place ----------------
__global__ void eg_kernel(float* __restrict__ a, const float* __restrict__ A_log,
                          const float* __restrict__ dt_bias, int n)
{
    int i = blockIdx.x * blockDim.x + threadIdx.x;
    if (i >= n) return;
    int d = i % D;
    int h = (i / D) % H;
    float z = a[i] + dt_bias[h * D + d];
    float sp = (z > 20.f) ? z : log1pf(expf(z));
    a[i] = expf(-expf(A_log[h]) * sp);
}

// ---------------- DPP wave64 reduction ----------------
template <int CTRL>
__device__ __forceinline__ float dpp_add(float x) {
    int y = __builtin_amdgcn_update_dpp(0, __builtin_bit_cast(int, x),
                                        CTRL, 0xF, 0xF, false);
    return x + __builtin_bit_cast(float, y);
}
__device__ __forceinline__ float wave_sum(float x) {
    x = dpp_add<0x111>(x);   // row_shr:1
    x = dpp_add<0x112>(x);   // row_shr:2
    x = dpp_add<0x114>(x);   // row_shr:4
    x = dpp_add<0x118>(x);   // row_shr:8
    x = dpp_add<0x142>(x);   // row_bcast:15
    x = dpp_add<0x143>(x);   // row_bcast:31
    return __builtin_bit_cast(float,
        __builtin_amdgcn_readlane(__builtin_bit_cast(int, x), 63));
}

// ---------------- gated delta-rule recurrence, LDS group-pipelined ----------
// 4 waves/block share one (b,h), each wave owns one value-column. Per group of
// 8 steps: one barrier, then each wave async-stages one slab (k/q/eg/v) of the
// NEXT group via global_load_lds into the other LDS buffer, then computes 8
// steps from the current buffer. The barrier's vmcnt(0) drain only covers
// loads issued a full group (~1200 cyc) earlier -> latency hidden (m97 shape).
__global__ __launch_bounds__(256) void recur_cols_kernel(const float* __restrict__ Q,
                                                         const float* __restrict__ Kc,
                                                         const float* __restrict__ V,
                                                         const float* __restrict__ EG,
                                                         const float* __restrict__ BETA,
                                                         float* __restrict__ O,
                                                         int T)
{
    __shared__ __align__(16) float lds[2][4][G][128];  // [buf][slab k,q,e,v][step][d] 32 KB
    __shared__ __align__(16) float ldsb[2][64];        // beta slab (8 used, padded)

    int wid = threadIdx.x >> 6;
    int lane = threadIdx.x & 63;
    int gw = blockIdx.x * 4 + wid;
    int bh = gw >> 7;
    int col = gw & 127;
    int b = bh >> 3, h = bh & 7;

    size_t base = ((size_t)b * T * H + h) * D;
    const char* slab0;
    if (wid == 0)      slab0 = (const char*)(Kc + base);
    else if (wid == 1) slab0 = (const char*)(Q + base);
    else if (wid == 2) slab0 = (const char*)(EG + base);
    else               slab0 = (const char*)(V + base);
    const char* betaPtr = (const char*)(BETA + (size_t)b * T * H + h);
    float* Ob = O + base + col;

    int d0 = lane * 2;
    float S0 = 0.f, S1 = 0.f;
    const int strideT = H * D;          // 1024 floats = 4096 B
    int rsel = lane >> 5;               // 0/1: which step-row of the 1KB instr
    int seg = (lane & 31) * 16;         // byte offset within 512B row
    int ngroups = T / G;

    // ---- stage group 0 into buffer 0 ----
    {
        int t0 = 0;
#pragma unroll
        for (int j = 0; j < 4; ++j) {
            int t = t0 + j * 2 + rsel;
            async16(slab0 + (size_t)t * 4096 + seg, &lds[0][wid][j * 2][0]);
        }
        if (wid == 3) {
            int t = t0 + (lane & 7);
            async4(betaPtr + (size_t)t * (H * 4), &ldsb[0][0]);
        }
    }

    for (int g = 0; g < ngroups; ++g) {
        int bf = g & 1;
        __syncthreads();   // drains loads for group g (issued one group ago)
        if (g + 1 < ngroups) {
            int t0 = (g + 1) * G;
#pragma unroll
            for (int j = 0; j < 4; ++j) {
                int t = t0 + j * 2 + rsel;
                async16(slab0 + (size_t)t * 4096 + seg, &lds[bf ^ 1][wid][j * 2][0]);
            }
            if (wid == 3) {
                int t = t0 + (lane & 7);
                async4(betaPtr + (size_t)t * (H * 4), &ldsb[bf ^ 1][0]);
            }
        }
#pragma unroll
        for (int i = 0; i < G; ++i) {
            float2 kc = *(const float2*)&lds[bf][0][i][d0];
            float2 qc = *(const float2*)&lds[bf][1][i][d0];
            float2 ec = *(const float2*)&lds[bf][2][i][d0];
            float vc = lds[bf][3][i][col];
            float bc = ldsb[bf][i];
            S0 *= ec.x;
            S1 *= ec.y;
            float R1 = wave_sum(kc.x * S0 + kc.y * S1);       // k . S'
            float R2 = wave_sum(qc.x * S0 + qc.y * S1);       // q . S'
            float R3 = wave_sum(kc.x * qc.x + kc.y * qc.y);   // q . k
            float delta = bc * (vc - R1);
            S0 += kc.x * delta;
            S1 += kc.y * delta;
            if (lane == 0) Ob[(size_t)(g * G + i) * strideT] = R2 + R3 * delta;
        }
    }
}

// -------- out = rmsnorm(o)*w*sigmoid(gate) -> bf16 (for final MFMA GEMM) ----
__global__ __launch_bounds__(128) void outnorm_kernel(const float* __restrict__ O,
                                                      const float* __restrict__ GATE,
                                                      const float* __restrict__ w,
                                                      bhalf* __restrict__ Obf)
{
    int bid = blockIdx.x;
    int d = threadIdx.x;
    size_t base = (size_t)bid * D;
    float y = O[base + d];
    __shared__ float red[2];
    float ss = y * y;
#pragma unroll
    for (int s = 32; s > 0; s >>= 1) ss += __shfl_xor(ss, s, 64);
    if ((threadIdx.x & 63) == 0) red[threadIdx.x >> 6] = ss;
    __syncthreads();
    float tot = red[0] + red[1];
    float r = rsqrtf(tot * (1.f / D) + 1e-5f);
    float gz = GATE[base + d];
    float sg = 1.f / (1.f + expf(-gz));
    Obf[base + d] = (bhalf)(y * r * w[d] * sg);
}

extern "C" void kernel_launch(void* const* d_in, const int* in_sizes, int n_in,
                              void* d_out, int out_size, void* d_ws, size_t ws_size,
                              hipStream_t stream)
{
    const float* x       = (const float*)d_in[0];
    const float* Wq      = (const float*)d_in[1];
    const float* Wk      = (const float*)d_in[2];
    const float* Wv      = (const float*)d_in[3];
    const float* wq_conv = (const float*)d_in[4];
    const float* wk_conv = (const float*)d_in[5];
    const float* wv_conv = (const float*)d_in[6];
    const float* Wfa     = (const float*)d_in[7];
    const float* Wfb     = (const float*)d_in[8];
    const float* Wb      = (const float*)d_in[9];
    const float* Wga     = (const float*)d_in[10];
    const float* Wgb     = (const float*)d_in[11];
    const float* A_log   = (const float*)d_in[12];
    const float* dt_bias = (const float*)d_in[13];
    const float* o_norm_w= (const float*)d_in[14];
    const float* Wo      = (const float*)d_in[15];

    int BT = in_sizes[0] / HID;     // B*T
    int T = 1024;
    int B_ = BT / T;
    size_t M = (size_t)BT;
    size_t sz_big = M * HID;

    float* ws   = (float*)d_ws;
    float* Qp   = ws;
    float* Kp   = Qp + sz_big;
    float* Vp   = Kp + sz_big;
    float* Qc   = Vp + sz_big;
    float* Kc   = Qc + sz_big;
    float* Vc   = Kc + sz_big;
    float* XA   = Vc + sz_big;        // M*128
    float* XG   = XA + M * D;
    float* EGb  = XG + M * D;         // M*1024
    float* GATE = EGb + sz_big;
    float* BETA = GATE + sz_big;      // M*H
    float* Obuf = BETA + M * H;       // M*1024

    // bf16 aliases into dead regions (stream-ordered liveness checked):
    bhalf* xb  = (bhalf*)GATE;              // dead before GATE gemm writes
    bhalf* Wqb = (bhalf*)EGb;               // dead before EGb gemm writes
    bhalf* Wkb = Wqb + (size_t)HID * HID;
    bhalf* Wvb = Wkb + (size_t)HID * HID;
    bhalf* Wob = (bhalf*)Kp;                // Kp dead after conv-k
    bhalf* Obf = (bhalf*)Qc;                // Qc dead after recurrence

    dim3 blk(256);
    dim3 gSmall(D / 64, BT / 64);           // N=128
    dim3 gBigF(HID / 64, BT / 64);          // fp32 gemm, N=1024
    dim3 gMf(HID / 64, BT / 128);           // bf16 mfma gemm 128x64 tiles

    int nW = HID * HID;
    // casts
    cast_bf16<<<(int)((sz_big + 255) / 256), 256, 0, stream>>>(x, xb, (int)sz_big);
    cast_bf16<<<(nW + 255) / 256, 256, 0, stream>>>(Wq, Wqb, nW);
    cast_bf16<<<(nW + 255) / 256, 256, 0, stream>>>(Wk, Wkb, nW);
    cast_bf16<<<(nW + 255) / 256, 256, 0, stream>>>(Wv, Wvb, nW);

    // projections (bf16 MFMA)
    gemm_bf16_nt<<<gMf, blk, 0, stream>>>(xb, Wqb, Qp, BT, HID, HID);
    gemm_bf16_nt<<<gMf, blk, 0, stream>>>(xb, Wkb, Kp, BT, HID, HID);
    gemm_bf16_nt<<<gMf, blk, 0, stream>>>(xb, Wvb, Vp, BT, HID, HID);

    // decay/gate path stays fp32
    gemm_nt<<<gSmall, blk, 0, stream>>>(x, Wfa, XA, BT, D, HID);
    gemm_nt<<<gSmall, blk, 0, stream>>>(x, Wga, XG, BT, D, HID);
    beta_kernel<<<BT, 256, 0, stream>>>(x, Wb, BETA);

    // conv + silu (+norm)
    const float scale  = 0.08838834764831845f;   // D^-0.5
    const float scale2 = 1.0f / 128.0f;          // D^-1
    conv_kernel<<<BT * H, 128, 0, stream>>>(Qp, wq_conv, Qc, 1, scale2, T);
    conv_kernel<<<BT * H, 128, 0, stream>>>(Kp, wk_conv, Kc, 2, scale, T);
    conv_kernel<<<BT * H, 128, 0, stream>>>(Vp, wv_conv, Vc, 0, 1.f, T);

    // Wo cast (Kp now dead)
    cast_bf16<<<(nW + 255) / 256, 256, 0, stream>>>(Wo, Wob, nW);

    // low-rank heads (overwrite Wqb/Wkb/Wvb region + xb region — both dead)
    gemm_nt<<<gBigF, blk, 0, stream>>>(XA, Wfb, EGb, BT, HID, D);
    gemm_nt<<<gBigF, blk, 0, stream>>>(XG, Wgb, GATE, BT, HID, D);
    eg_kernel<<<(int)((sz_big + 255) / 256), 256, 0, stream>>>(EGb, A_log, dt_bias, (int)sz_big);

    // recurrence
    recur_cols_kernel<<<B_ * H * 32, 256, 0, stream>>>(Qc, Kc, Vc, EGb, BETA, Obuf, T);

    // output norm * gate -> bf16 (Qc region dead)
    outnorm_kernel<<<BT * H, 128, 0, stream>>>(Obuf, GATE, o_norm_w, Obf);

    // final projection (bf16 MFMA)
    gemm_bf16_nt<<<gMf, blk, 0, stream>>>(Obf, Wob, (float*)d_out, BT, HID, HID);
}

// Round 5
// 538.871 us; speedup vs baseline: 5.1001x; 1.1412x over previous
//
#include <hip/hip_runtime.h>
#include <hip/hip_bf16.h>
#include <math.h>

#define H 8
#define D 128
#define HID 1024
#define KCONV 4
#define G 8            // recurrence: steps per LDS group

typedef __bf16 bhalf;
typedef __bf16 bhalf8 __attribute__((ext_vector_type(8)));
typedef float f32x4 __attribute__((ext_vector_type(4)));

// ---- async global->LDS (direct-to-shared DMA, bypasses VGPRs) ----
__device__ __forceinline__ void async16(const void* g, void* l) {
    __builtin_amdgcn_global_load_lds(
        (const __attribute__((address_space(1))) void*)g,
        (__attribute__((address_space(3))) void*)l, 16, 0, 0);
}
__device__ __forceinline__ void async4(const void* g, void* l) {
    __builtin_amdgcn_global_load_lds(
        (const __attribute__((address_space(1))) void*)g,
        (__attribute__((address_space(3))) void*)l, 4, 0, 0);
}

// ---------------- bf16 MFMA GEMM: C[M,N] = A[M,K]*B[N,K]^T ----------------
// 128x64 tile, BK=32, 256 threads (4 waves, 2x2), global_load_lds staging.
// epi: 0 = fp32 store, 1 = eg transform (exp(-exp(A_log)*softplus(z+dt_bias)))
//      2 = bf16 store
__global__ __launch_bounds__(256) void gemm_bf16_nt(const bhalf* __restrict__ A,
                                                    const bhalf* __restrict__ B,
                                                    void* __restrict__ Cv,
                                                    int M, int N, int K, int epi,
                                                    const float* __restrict__ A_log,
                                                    const float* __restrict__ dt_bias)
{
    __shared__ __align__(16) bhalf As[128][32];   // 8 KB
    __shared__ __align__(16) bhalf Bs[64][32];    // 4 KB
    int tid = threadIdx.x;
    int wid = tid >> 6, lane = tid & 63;
    int rowBase = blockIdx.y * 128;
    int colBase = blockIdx.x * 64;
    int wm = wid >> 1, wn = wid & 1;

    f32x4 acc[4][2] = {};

    int r = lane >> 2;          // 16 rows per 1KB instr
    int cseg = lane & 3;        // 16B segment within 64B row

    for (int k0 = 0; k0 < K; k0 += 32) {
        __syncthreads();
#pragma unroll
        for (int s = 0; s < 3; ++s) {
            int j = wid * 3 + s;            // 12 instrs: 8 A + 4 B
            if (j < 8) {
                const bhalf* ga = A + (size_t)(rowBase + j * 16 + r) * K + k0 + cseg * 8;
                async16(ga, &As[j * 16][0]);
            } else {
                int jb = j - 8;
                const bhalf* ga = B + (size_t)(colBase + jb * 16 + r) * K + k0 + cseg * 8;
                async16(ga, &Bs[jb * 16][0]);
            }
        }
        __syncthreads();
        int mq = lane & 15, kq = (lane >> 4) * 8;
        bhalf8 a[4], bfr[2];
#pragma unroll
        for (int mt = 0; mt < 4; ++mt)
            a[mt] = *(const bhalf8*)&As[wm * 64 + mt * 16 + mq][kq];
#pragma unroll
        for (int nt = 0; nt < 2; ++nt)
            bfr[nt] = *(const bhalf8*)&Bs[wn * 32 + nt * 16 + mq][kq];
#pragma unroll
        for (int mt = 0; mt < 4; ++mt)
#pragma unroll
            for (int nt = 0; nt < 2; ++nt)
                acc[mt][nt] = __builtin_amdgcn_mfma_f32_16x16x32_bf16(
                    a[mt], bfr[nt], acc[mt][nt], 0, 0, 0);
    }
    int rquad = (lane >> 4) * 4;
#pragma unroll
    for (int mt = 0; mt < 4; ++mt) {
        int m0 = rowBase + wm * 64 + mt * 16 + rquad;
#pragma unroll
        for (int nt = 0; nt < 2; ++nt) {
            int c = colBase + wn * 32 + (lane & 15) + nt * 16;
#pragma unroll
            for (int rr = 0; rr < 4; ++rr) {
                float val = acc[mt][nt][rr];
                size_t idx = (size_t)(m0 + rr) * N + c;
                if (epi == 0) {
                    ((float*)Cv)[idx] = val;
                } else if (epi == 1) {
                    int h = c >> 7, d = c & 127;
                    float z = val + dt_bias[h * D + d];
                    float sp = (z > 20.f) ? z : log1pf(expf(z));
                    ((float*)Cv)[idx] = expf(-expf(A_log[h]) * sp);
                } else {
                    ((bhalf*)Cv)[idx] = (bhalf)val;
                }
            }
        }
    }
}

// ---------------- casts ----------------
__global__ void cast1(const float* __restrict__ s, bhalf* __restrict__ d, int n)
{
    int i = blockIdx.x * blockDim.x + threadIdx.x;
    if (i < n) d[i] = (bhalf)s[i];
}
__global__ void cast4(const float* __restrict__ s0, const float* __restrict__ s1,
                      const float* __restrict__ s2, const float* __restrict__ s3,
                      bhalf* __restrict__ d0, bhalf* __restrict__ d1,
                      bhalf* __restrict__ d2, bhalf* __restrict__ d3, int n)
{
    int i = blockIdx.x * blockDim.x + threadIdx.x;
    if (i >= n) return;
    int a = blockIdx.y;
    if (a == 0) d0[i] = (bhalf)s0[i];
    else if (a == 1) d1[i] = (bhalf)s1[i];
    else if (a == 2) d2[i] = (bhalf)s2[i];
    else d3[i] = (bhalf)s3[i];
}

// ---------------- beta = sigmoid(x @ Wb^T), Wb: (H, HID) ----------------
__global__ __launch_bounds__(256) void beta_kernel(const float* __restrict__ x,
                                                   const float* __restrict__ Wb,
                                                   float* __restrict__ beta)
{
    int row = blockIdx.x;
    int tid = threadIdx.x;
    int h = tid >> 5;
    int lane = tid & 31;
    const float* xr = x + (size_t)row * HID;
    const float* wr = Wb + (size_t)h * HID;
    float acc = 0.f;
    for (int k = lane; k < HID; k += 32) acc += xr[k] * wr[k];
#pragma unroll
    for (int s = 16; s > 0; s >>= 1) acc += __shfl_xor(acc, s, 64);
    if (lane == 0) beta[(size_t)row * H + h] = 1.f / (1.f + expf(-acc));
}

// ------- fused depthwise causal conv (K=4) + SiLU (+ rmsnorm*scale) --------
// grid.y: 0 = q (norm, scale 1/D), 1 = k (norm, scale D^-0.5), 2 = v (plain)
__global__ __launch_bounds__(128) void conv3_kernel(const float* __restrict__ Qp,
                                                    const float* __restrict__ Kp,
                                                    const float* __restrict__ Vp,
                                                    const float* __restrict__ wq,
                                                    const float* __restrict__ wk,
                                                    const float* __restrict__ wv,
                                                    float* __restrict__ Qc,
                                                    float* __restrict__ Kc,
                                                    float* __restrict__ Vc,
                                                    int T)
{
    int which = blockIdx.y;
    const float* P; const float* w; float* out; int mode; float scale;
    if (which == 0)      { P = Qp; w = wq; out = Qc; mode = 1; scale = 1.0f / 128.0f; }
    else if (which == 1) { P = Kp; w = wk; out = Kc; mode = 1; scale = 0.08838834764831845f; }
    else                 { P = Vp; w = wv; out = Vc; mode = 0; scale = 1.f; }

    int bid = blockIdx.x;
    int h = bid % H;
    int t = (bid / H) % T;
    int b = bid / (H * T);
    int d = threadIdx.x;
    int c = h * D + d;
    const float* base = P + (size_t)b * T * HID;
    float acc = 0.f;
#pragma unroll
    for (int j = 0; j < KCONV; ++j) {
        int tt = t - (KCONV - 1) + j;
        float xv = (tt >= 0) ? base[(size_t)tt * HID + c] : 0.f;
        acc += xv * w[c * KCONV + j];
    }
    float y = acc / (1.f + expf(-acc));
    if (mode) {
        __shared__ float red[2];
        float ss = y * y;
#pragma unroll
        for (int s = 32; s > 0; s >>= 1) ss += __shfl_xor(ss, s, 64);
        if ((threadIdx.x & 63) == 0) red[threadIdx.x >> 6] = ss;
        __syncthreads();
        float tot = red[0] + red[1];
        float r = rsqrtf(tot * (1.f / D) + 1e-6f);
        y = y * r * scale;
    }
    out[(size_t)bid * D + d] = y;
}

// ---------------- DPP wave64 reduction ----------------
template <int CTRL>
__device__ __forceinline__ float dpp_add(float x) {
    int y = __builtin_amdgcn_update_dpp(0, __builtin_bit_cast(int, x),
                                        CTRL, 0xF, 0xF, false);
    return x + __builtin_bit_cast(float, y);
}
// after this chain the full-wave sum is valid in lane 63
__device__ __forceinline__ float wave_sum63(float x) {
    x = dpp_add<0x111>(x);   // row_shr:1
    x = dpp_add<0x112>(x);   // row_shr:2
    x = dpp_add<0x114>(x);   // row_shr:4
    x = dpp_add<0x118>(x);   // row_shr:8
    x = dpp_add<0x142>(x);   // row_bcast:15
    x = dpp_add<0x143>(x);   // row_bcast:31
    return x;
}
__device__ __forceinline__ float wave_sum(float x) {
    return __builtin_bit_cast(float,
        __builtin_amdgcn_readlane(__builtin_bit_cast(int, wave_sum63(x)), 63));
}

// ---------------- gated delta-rule recurrence, LDS group-pipelined ----------
// 4 waves/block share one (b,h), each wave owns one value-column. Per group of
// 8 steps: barrier, async-stage NEXT group into other LDS buffer, compute 8
// steps. Critical chain per step: fma(R1) -> 6 DPP -> readlane -> delta ->
// k*delta -> fma(S). Decay folded into the R1 weights (k.e precomputed) and
// the S update (fma form). Output o = q.S_new reduced to lane 63 and stored
// there -- entirely off the critical path.
__global__ __launch_bounds__(256) void recur_cols_kernel(const float* __restrict__ Q,
                                                         const float* __restrict__ Kc,
                                                         const float* __restrict__ V,
                                                         const float* __restrict__ EG,
                                                         const float* __restrict__ BETA,
                                                         float* __restrict__ O,
                                                         int T)
{
    __shared__ __align__(16) float lds[2][4][G][128];  // 32 KB
    __shared__ __align__(16) float ldsb[2][64];        // beta slab

    int wid = threadIdx.x >> 6;
    int lane = threadIdx.x & 63;
    int gw = blockIdx.x * 4 + wid;
    int bh = gw >> 7;
    int col = gw & 127;
    int b = bh >> 3, h = bh & 7;

    size_t base = ((size_t)b * T * H + h) * D;
    const char* slab0;
    if (wid == 0)      slab0 = (const char*)(Kc + base);
    else if (wid == 1) slab0 = (const char*)(Q + base);
    else if (wid == 2) slab0 = (const char*)(EG + base);
    else               slab0 = (const char*)(V + base);
    const char* betaPtr = (const char*)(BETA + (size_t)b * T * H + h);
    float* Ob = O + base + col;

    int d0 = lane * 2;
    float S0 = 0.f, S1 = 0.f;
    const int strideT = H * D;          // 1024 floats = 4096 B
    int rsel = lane >> 5;
    int seg = (lane & 31) * 16;
    int ngroups = T / G;

    // ---- stage group 0 into buffer 0 ----
#pragma unroll
    for (int j = 0; j < 4; ++j) {
        int t = j * 2 + rsel;
        async16(slab0 + (size_t)t * 4096 + seg, &lds[0][wid][j * 2][0]);
    }
    if (wid == 3) {
        int t = lane & 7;
        async4(betaPtr + (size_t)t * (H * 4), &ldsb[0][0]);
    }

    for (int g = 0; g < ngroups; ++g) {
        int bf = g & 1;
        __syncthreads();   // drains loads for group g (issued one group ago)
        if (g + 1 < ngroups) {
            int t0 = (g + 1) * G;
#pragma unroll
            for (int j = 0; j < 4; ++j) {
                int t = t0 + j * 2 + rsel;
                async16(slab0 + (size_t)t * 4096 + seg, &lds[bf ^ 1][wid][j * 2][0]);
            }
            if (wid == 3) {
                int t = t0 + (lane & 7);
                async4(betaPtr + (size_t)t * (H * 4), &ldsb[bf ^ 1][0]);
            }
        }
#pragma unroll
        for (int i = 0; i < G; ++i) {
            float2 kc = *(const float2*)&lds[bf][0][i][d0];
            float2 qc = *(const float2*)&lds[bf][1][i][d0];
            float2 ec = *(const float2*)&lds[bf][2][i][d0];
            float vc = lds[bf][3][i][col];
            float bc = ldsb[bf][i];
            // off-chain: decay-folded R1 weights
            float kex = kc.x * ec.x;
            float key = kc.y * ec.y;
            // chain: R1 = (k.e).S
            float R1 = wave_sum(kex * S0 + key * S1);
            float delta = bc * (vc - R1);
            S0 = fmaf(ec.x, S0, kc.x * delta);
            S1 = fmaf(ec.y, S1, kc.y * delta);
            // off-chain: output from S_new, reduced into lane 63
            float o63 = wave_sum63(qc.x * S0 + qc.y * S1);
            if (lane == 63) Ob[(size_t)(g * G + i) * strideT] = o63;
        }
    }
}

// -------- out = rmsnorm(o)*w*sigmoid(gate) -> bf16 (for final MFMA GEMM) ----
__global__ __launch_bounds__(128) void outnorm_kernel(const float* __restrict__ O,
                                                      const float* __restrict__ GATE,
                                                      const float* __restrict__ w,
                                                      bhalf* __restrict__ Obf)
{
    int bid = blockIdx.x;
    int d = threadIdx.x;
    size_t base = (size_t)bid * D;
    float y = O[base + d];
    __shared__ float red[2];
    float ss = y * y;
#pragma unroll
    for (int s = 32; s > 0; s >>= 1) ss += __shfl_xor(ss, s, 64);
    if ((threadIdx.x & 63) == 0) red[threadIdx.x >> 6] = ss;
    __syncthreads();
    float tot = red[0] + red[1];
    float r = rsqrtf(tot * (1.f / D) + 1e-5f);
    float gz = GATE[base + d];
    float sg = 1.f / (1.f + expf(-gz));
    Obf[base + d] = (bhalf)(y * r * w[d] * sg);
}

extern "C" void kernel_launch(void* const* d_in, const int* in_sizes, int n_in,
                              void* d_out, int out_size, void* d_ws, size_t ws_size,
                              hipStream_t stream)
{
    const float* x       = (const float*)d_in[0];
    const float* Wq      = (const float*)d_in[1];
    const float* Wk      = (const float*)d_in[2];
    const float* Wv      = (const float*)d_in[3];
    const float* wq_conv = (const float*)d_in[4];
    const float* wk_conv = (const float*)d_in[5];
    const float* wv_conv = (const float*)d_in[6];
    const float* Wfa     = (const float*)d_in[7];
    const float* Wfb     = (const float*)d_in[8];
    const float* Wb      = (const float*)d_in[9];
    const float* Wga     = (const float*)d_in[10];
    const float* Wgb     = (const float*)d_in[11];
    const float* A_log   = (const float*)d_in[12];
    const float* dt_bias = (const float*)d_in[13];
    const float* o_norm_w= (const float*)d_in[14];
    const float* Wo      = (const float*)d_in[15];

    int BT = in_sizes[0] / HID;     // B*T
    int T = 1024;
    int B_ = BT / T;
    size_t M = (size_t)BT;
    size_t sz_big = M * HID;
    const int nW = HID * HID;       // 1M
    const int nS = D * HID;         // 131072

    // ---- explicit workspace layout (no aliasing) ----
    float* fp = (float*)d_ws;
    float* Qp   = fp;               fp += sz_big;
    float* Kp   = fp;               fp += sz_big;
    float* Vp   = fp;               fp += sz_big;
    float* Qc   = fp;               fp += sz_big;
    float* Kc   = fp;               fp += sz_big;
    float* Vc   = fp;               fp += sz_big;
    float* EGb  = fp;               fp += sz_big;
    float* GATE = fp;               fp += sz_big;
    float* Obuf = fp;               fp += sz_big;
    float* BETA = fp;               fp += M * H;
    bhalf* bp = (bhalf*)fp;
    bhalf* xb   = bp;               bp += sz_big;
    bhalf* Wqb  = bp;               bp += nW;
    bhalf* Wkb  = bp;               bp += nW;
    bhalf* Wvb  = bp;               bp += nW;
    bhalf* Wob  = bp;               bp += nW;
    bhalf* Wfab = bp;               bp += nS;
    bhalf* Wgab = bp;               bp += nS;
    bhalf* Wfbb = bp;               bp += nS;
    bhalf* Wgbb = bp;               bp += nS;
    bhalf* XAb  = bp;               bp += M * D;
    bhalf* XGb  = bp;               bp += M * D;
    bhalf* Obf  = bp;               bp += sz_big;

    dim3 blk(256);
    dim3 gProj(HID / 64, BT / 128);         // N=1024 mfma tiles
    dim3 gXA(D / 64, BT / 128);             // N=128

    // casts (3 launches)
    cast1<<<(int)((sz_big + 255) / 256), 256, 0, stream>>>(x, xb, (int)sz_big);
    cast4<<<dim3((nW + 255) / 256, 4), 256, 0, stream>>>(Wq, Wk, Wv, Wo,
                                                         Wqb, Wkb, Wvb, Wob, nW);
    cast4<<<dim3((nS + 255) / 256, 4), 256, 0, stream>>>(Wfa, Wga, Wfb, Wgb,
                                                         Wfab, Wgab, Wfbb, Wgbb, nS);

    // projections (bf16 MFMA)
    gemm_bf16_nt<<<gProj, blk, 0, stream>>>(xb, Wqb, Qp, BT, HID, HID, 0, nullptr, nullptr);
    gemm_bf16_nt<<<gProj, blk, 0, stream>>>(xb, Wkb, Kp, BT, HID, HID, 0, nullptr, nullptr);
    gemm_bf16_nt<<<gProj, blk, 0, stream>>>(xb, Wvb, Vp, BT, HID, HID, 0, nullptr, nullptr);

    // decay/gate low-rank first stage (bf16 out for second stage)
    gemm_bf16_nt<<<gXA, blk, 0, stream>>>(xb, Wfab, XAb, BT, D, HID, 2, nullptr, nullptr);
    gemm_bf16_nt<<<gXA, blk, 0, stream>>>(xb, Wgab, XGb, BT, D, HID, 2, nullptr, nullptr);
    beta_kernel<<<BT, 256, 0, stream>>>(x, Wb, BETA);

    // conv + silu (+norm) fused, one launch
    conv3_kernel<<<dim3(BT * H, 3), 128, 0, stream>>>(Qp, Kp, Vp,
                                                      wq_conv, wk_conv, wv_conv,
                                                      Qc, Kc, Vc, T);

    // second stage: EGb (with fused eg transform) and GATE
    gemm_bf16_nt<<<gProj, blk, 0, stream>>>(XAb, Wfbb, EGb, BT, HID, D, 1, A_log, dt_bias);
    gemm_bf16_nt<<<gProj, blk, 0, stream>>>(XGb, Wgbb, GATE, BT, HID, D, 0, nullptr, nullptr);

    // recurrence
    recur_cols_kernel<<<B_ * H * 32, 256, 0, stream>>>(Qc, Kc, Vc, EGb, BETA, Obuf, T);

    // output norm * gate -> bf16
    outnorm_kernel<<<BT * H, 128, 0, stream>>>(Obuf, GATE, o_norm_w, Obf);

    // final projection (bf16 MFMA)
    gemm_bf16_nt<<<gProj, blk, 0, stream>>>(Obf, Wob, (float*)d_out, BT, HID, HID, 0, nullptr, nullptr);
}

// Round 6
// 460.965 us; speedup vs baseline: 5.9620x; 1.1690x over previous
//
#include <hip/hip_runtime.h>
#include <hip/hip_bf16.h>
#include <math.h>

#define H 8
#define D 128
#define HID 1024
#define KCONV 4
#define G 8            // recurrence: steps per LDS group

typedef __bf16 bhalf;
typedef __bf16 bhalf8 __attribute__((ext_vector_type(8)));
typedef float f32x4 __attribute__((ext_vector_type(4)));

// ---- async global->LDS (direct-to-shared DMA, bypasses VGPRs) ----
__device__ __forceinline__ void async16(const void* g, void* l) {
    __builtin_amdgcn_global_load_lds(
        (const __attribute__((address_space(1))) void*)g,
        (__attribute__((address_space(3))) void*)l, 16, 0, 0);
}
__device__ __forceinline__ void async4(const void* g, void* l) {
    __builtin_amdgcn_global_load_lds(
        (const __attribute__((address_space(1))) void*)g,
        (__attribute__((address_space(3))) void*)l, 4, 0, 0);
}

// ---------------- bf16 MFMA GEMM: C[M,N] = A[M,K]*B[N,K]^T ----------------
// 128x64 tile, BK=32, 256 threads (4 waves, 2x2), global_load_lds staging.
// Generic lda/ldb/ldc. blockIdx.z==1 selects the second (A2,B2,C2,epi2) job.
// epi: 0 = fp32 store, 1 = eg transform, 2 = bf16 store
__global__ __launch_bounds__(256) void gemm_bf16_nt(const bhalf* A, const bhalf* B,
                                                    void* Cv,
                                                    int M, int N, int K,
                                                    int lda, int ldb, int ldc, int epi,
                                                    const float* __restrict__ A_log,
                                                    const float* __restrict__ dt_bias,
                                                    const bhalf* A2, const bhalf* B2,
                                                    void* C2, int epi2)
{
    if (blockIdx.z) { A = A2; B = B2; Cv = C2; epi = epi2; }
    __shared__ __align__(16) bhalf As[128][32];   // 8 KB
    __shared__ __align__(16) bhalf Bs[64][32];    // 4 KB
    int tid = threadIdx.x;
    int wid = tid >> 6, lane = tid & 63;
    int rowBase = blockIdx.y * 128;
    int colBase = blockIdx.x * 64;
    int wm = wid >> 1, wn = wid & 1;

    f32x4 acc[4][2] = {};

    int r = lane >> 2;          // 16 rows per 1KB instr
    int cseg = lane & 3;        // 16B segment within 64B row

    for (int k0 = 0; k0 < K; k0 += 32) {
        __syncthreads();
#pragma unroll
        for (int s = 0; s < 3; ++s) {
            int j = wid * 3 + s;            // 12 instrs: 8 A + 4 B
            if (j < 8) {
                const bhalf* ga = A + (size_t)(rowBase + j * 16 + r) * lda + k0 + cseg * 8;
                async16(ga, &As[j * 16][0]);
            } else {
                int jb = j - 8;
                const bhalf* ga = B + (size_t)(colBase + jb * 16 + r) * ldb + k0 + cseg * 8;
                async16(ga, &Bs[jb * 16][0]);
            }
        }
        __syncthreads();
        int mq = lane & 15, kq = (lane >> 4) * 8;
        bhalf8 a[4], bfr[2];
#pragma unroll
        for (int mt = 0; mt < 4; ++mt)
            a[mt] = *(const bhalf8*)&As[wm * 64 + mt * 16 + mq][kq];
#pragma unroll
        for (int nt = 0; nt < 2; ++nt)
            bfr[nt] = *(const bhalf8*)&Bs[wn * 32 + nt * 16 + mq][kq];
#pragma unroll
        for (int mt = 0; mt < 4; ++mt)
#pragma unroll
            for (int nt = 0; nt < 2; ++nt)
                acc[mt][nt] = __builtin_amdgcn_mfma_f32_16x16x32_bf16(
                    a[mt], bfr[nt], acc[mt][nt], 0, 0, 0);
    }
    int rquad = (lane >> 4) * 4;
#pragma unroll
    for (int mt = 0; mt < 4; ++mt) {
        int m0 = rowBase + wm * 64 + mt * 16 + rquad;
#pragma unroll
        for (int nt = 0; nt < 2; ++nt) {
            int c = colBase + wn * 32 + (lane & 15) + nt * 16;
#pragma unroll
            for (int rr = 0; rr < 4; ++rr) {
                float val = acc[mt][nt][rr];
                size_t idx = (size_t)(m0 + rr) * ldc + c;
                if (epi == 0) {
                    ((float*)Cv)[idx] = val;
                } else if (epi == 1) {
                    int h = c >> 7, d = c & 127;
                    float z = val + dt_bias[h * D + d];
                    float sp = (z > 20.f) ? z : log1pf(expf(z));
                    ((float*)Cv)[idx] = expf(-expf(A_log[h]) * sp);
                } else {
                    ((bhalf*)Cv)[idx] = (bhalf)val;
                }
            }
        }
    }
}

// ---------------- casts ----------------
__global__ void cast1(const float* __restrict__ s, bhalf* __restrict__ d, int n)
{
    int i = blockIdx.x * blockDim.x + threadIdx.x;
    if (i < n) d[i] = (bhalf)s[i];
}
__global__ void cast4(const float* __restrict__ s0, const float* __restrict__ s1,
                      const float* __restrict__ s2, const float* __restrict__ s3,
                      bhalf* __restrict__ d0, bhalf* __restrict__ d1,
                      bhalf* __restrict__ d2, bhalf* __restrict__ d3, int n)
{
    int i = blockIdx.x * blockDim.x + threadIdx.x;
    if (i >= n) return;
    int a = blockIdx.y;
    if (a == 0) d0[i] = (bhalf)s0[i];
    else if (a == 1) d1[i] = (bhalf)s1[i];
    else if (a == 2) d2[i] = (bhalf)s2[i];
    else d3[i] = (bhalf)s3[i];
}

// ---------------- beta = sigmoid(x @ Wb^T), Wb: (H, HID) ----------------
__global__ __launch_bounds__(256) void beta_kernel(const float* __restrict__ x,
                                                   const float* __restrict__ Wb,
                                                   float* __restrict__ beta)
{
    int row = blockIdx.x;
    int tid = threadIdx.x;
    int h = tid >> 5;
    int lane = tid & 31;
    const float* xr = x + (size_t)row * HID;
    const float* wr = Wb + (size_t)h * HID;
    float acc = 0.f;
    for (int k = lane; k < HID; k += 32) acc += xr[k] * wr[k];
#pragma unroll
    for (int s = 16; s > 0; s >>= 1) acc += __shfl_xor(acc, s, 64);
    if (lane == 0) beta[(size_t)row * H + h] = 1.f / (1.f + expf(-acc));
}

// ------- fused depthwise causal conv (K=4) + SiLU (+ rmsnorm*scale) --------
// P = QKV fused projection (row stride 3072). grid.y: 0=q, 1=k, 2=v
__global__ __launch_bounds__(128) void conv3_kernel(const float* __restrict__ QKV,
                                                    const float* __restrict__ wq,
                                                    const float* __restrict__ wk,
                                                    const float* __restrict__ wv,
                                                    float* __restrict__ Qc,
                                                    float* __restrict__ Kc,
                                                    float* __restrict__ Vc,
                                                    int T)
{
    int which = blockIdx.y;
    const float* w; float* out; int mode; float scale;
    if (which == 0)      { w = wq; out = Qc; mode = 1; scale = 1.0f / 128.0f; }
    else if (which == 1) { w = wk; out = Kc; mode = 1; scale = 0.08838834764831845f; }
    else                 { w = wv; out = Vc; mode = 0; scale = 1.f; }

    int bid = blockIdx.x;
    int h = bid % H;
    int t = (bid / H) % T;
    int b = bid / (H * T);
    int d = threadIdx.x;
    int c = h * D + d;
    const float* base = QKV + (size_t)b * T * 3072 + which * 1024 + c;
    float acc = 0.f;
#pragma unroll
    for (int j = 0; j < KCONV; ++j) {
        int tt = t - (KCONV - 1) + j;
        float xv = (tt >= 0) ? base[(size_t)tt * 3072] : 0.f;
        acc += xv * w[c * KCONV + j];
    }
    float y = acc / (1.f + expf(-acc));
    if (mode) {
        __shared__ float red[2];
        float ss = y * y;
#pragma unroll
        for (int s = 32; s > 0; s >>= 1) ss += __shfl_xor(ss, s, 64);
        if ((threadIdx.x & 63) == 0) red[threadIdx.x >> 6] = ss;
        __syncthreads();
        float tot = red[0] + red[1];
        float r = rsqrtf(tot * (1.f / D) + 1e-6f);
        y = y * r * scale;
    }
    out[(size_t)bid * D + d] = y;
}

// ---------------- DPP wave64 reduction ----------------
template <int CTRL>
__device__ __forceinline__ float dpp_add(float x) {
    int y = __builtin_amdgcn_update_dpp(0, __builtin_bit_cast(int, x),
                                        CTRL, 0xF, 0xF, false);
    return x + __builtin_bit_cast(float, y);
}
// after this chain the full-wave sum is valid in lane 63
__device__ __forceinline__ float wave_sum63(float x) {
    x = dpp_add<0x111>(x);   // row_shr:1
    x = dpp_add<0x112>(x);   // row_shr:2
    x = dpp_add<0x114>(x);   // row_shr:4
    x = dpp_add<0x118>(x);   // row_shr:8
    x = dpp_add<0x142>(x);   // row_bcast:15
    x = dpp_add<0x143>(x);   // row_bcast:31
    return x;
}
__device__ __forceinline__ float wave_sum(float x) {
    return __builtin_bit_cast(float,
        __builtin_amdgcn_readlane(__builtin_bit_cast(int, wave_sum63(x)), 63));
}

// ---------------- gated delta-rule recurrence, LDS group-pipelined ----------
// 4 waves/block share one (b,h), each wave owns one value-column.
// __launch_bounds__(256,2): grid gives exactly 2 blocks/CU, so let the
// register allocator use ~128 VGPRs — the whole group's operands are
// bulk-read from LDS into registers right after the barrier (back-to-back
// ds_reads, fine-grained lgkmcnt), then 8 steps run from registers with only
// the DPP reduction chain on the critical path.
__global__ __launch_bounds__(256, 2) void recur_cols_kernel(const float* __restrict__ Q,
                                                            const float* __restrict__ Kc,
                                                            const float* __restrict__ V,
                                                            const float* __restrict__ EG,
                                                            const float* __restrict__ BETA,
                                                            float* __restrict__ O,
                                                            int T)
{
    __shared__ __align__(16) float lds[2][4][G][128];  // 32 KB
    __shared__ __align__(16) float ldsb[2][64];        // beta slab

    int wid = threadIdx.x >> 6;
    int lane = threadIdx.x & 63;
    int gw = blockIdx.x * 4 + wid;
    int bh = gw >> 7;
    int col = gw & 127;
    int b = bh >> 3, h = bh & 7;

    size_t base = ((size_t)b * T * H + h) * D;
    const char* slab0;
    if (wid == 0)      slab0 = (const char*)(Kc + base);
    else if (wid == 1) slab0 = (const char*)(Q + base);
    else if (wid == 2) slab0 = (const char*)(EG + base);
    else               slab0 = (const char*)(V + base);
    const char* betaPtr = (const char*)(BETA + (size_t)b * T * H + h);
    float* Ob = O + base + col;

    int d0 = lane * 2;
    float S0 = 0.f, S1 = 0.f;
    const int strideT = H * D;          // 1024 floats = 4096 B
    int rsel = lane >> 5;
    int seg = (lane & 31) * 16;
    int ngroups = T / G;

    // ---- stage group 0 into buffer 0 ----
#pragma unroll
    for (int j = 0; j < 4; ++j) {
        int t = j * 2 + rsel;
        async16(slab0 + (size_t)t * 4096 + seg, &lds[0][wid][j * 2][0]);
    }
    if (wid == 3) {
        int t = lane & 7;
        async4(betaPtr + (size_t)t * (H * 4), &ldsb[0][0]);
    }

    for (int g = 0; g < ngroups; ++g) {
        int bf = g & 1;
        __syncthreads();   // drains loads for group g (issued one group ago)
        if (g + 1 < ngroups) {
            int t0 = (g + 1) * G;
#pragma unroll
            for (int j = 0; j < 4; ++j) {
                int t = t0 + j * 2 + rsel;
                async16(slab0 + (size_t)t * 4096 + seg, &lds[bf ^ 1][wid][j * 2][0]);
            }
            if (wid == 3) {
                int t = t0 + (lane & 7);
                async4(betaPtr + (size_t)t * (H * 4), &ldsb[bf ^ 1][0]);
            }
        }
        // ---- bulk operand load: whole group into registers ----
        float2 kg[G], qg[G], eg[G];
        float vg[G], bg[G];
#pragma unroll
        for (int i = 0; i < G; ++i) {
            kg[i] = *(const float2*)&lds[bf][0][i][d0];
            qg[i] = *(const float2*)&lds[bf][1][i][d0];
            eg[i] = *(const float2*)&lds[bf][2][i][d0];
            vg[i] = lds[bf][3][i][col];
            bg[i] = ldsb[bf][i];
        }
#pragma unroll
        for (int i = 0; i < G; ++i) {
            // off-chain: beta- and decay-folded weights
            float kbx = kg[i].x * eg[i].x * bg[i];
            float kby = kg[i].y * eg[i].y * bg[i];
            float bv  = bg[i] * vg[i];
            // chain: R1 = b*(k.e . S); delta = b*v - R1
            float R1 = wave_sum(kbx * S0 + kby * S1);
            float delta = bv - R1;
            S0 = fmaf(eg[i].x, S0, kg[i].x * delta);
            S1 = fmaf(eg[i].y, S1, kg[i].y * delta);
            // off-chain: output from S_new, reduced into lane 63
            float o63 = wave_sum63(qg[i].x * S0 + qg[i].y * S1);
            if (lane == 63) Ob[(size_t)(g * G + i) * strideT] = o63;
        }
    }
}

// -------- out = rmsnorm(o)*w*sigmoid(gate) -> bf16 (for final MFMA GEMM) ----
__global__ __launch_bounds__(128) void outnorm_kernel(const float* __restrict__ O,
                                                      const float* __restrict__ GATE,
                                                      const float* __restrict__ w,
                                                      bhalf* __restrict__ Obf)
{
    int bid = blockIdx.x;
    int d = threadIdx.x;
    size_t base = (size_t)bid * D;
    float y = O[base + d];
    __shared__ float red[2];
    float ss = y * y;
#pragma unroll
    for (int s = 32; s > 0; s >>= 1) ss += __shfl_xor(ss, s, 64);
    if ((threadIdx.x & 63) == 0) red[threadIdx.x >> 6] = ss;
    __syncthreads();
    float tot = red[0] + red[1];
    float r = rsqrtf(tot * (1.f / D) + 1e-5f);
    float gz = GATE[base + d];
    float sg = 1.f / (1.f + expf(-gz));
    Obf[base + d] = (bhalf)(y * r * w[d] * sg);
}

extern "C" void kernel_launch(void* const* d_in, const int* in_sizes, int n_in,
                              void* d_out, int out_size, void* d_ws, size_t ws_size,
                              hipStream_t stream)
{
    const float* x       = (const float*)d_in[0];
    const float* Wq      = (const float*)d_in[1];
    const float* Wk      = (const float*)d_in[2];
    const float* Wv      = (const float*)d_in[3];
    const float* wq_conv = (const float*)d_in[4];
    const float* wk_conv = (const float*)d_in[5];
    const float* wv_conv = (const float*)d_in[6];
    const float* Wfa     = (const float*)d_in[7];
    const float* Wfb     = (const float*)d_in[8];
    const float* Wb      = (const float*)d_in[9];
    const float* Wga     = (const float*)d_in[10];
    const float* Wgb     = (const float*)d_in[11];
    const float* A_log   = (const float*)d_in[12];
    const float* dt_bias = (const float*)d_in[13];
    const float* o_norm_w= (const float*)d_in[14];
    const float* Wo      = (const float*)d_in[15];

    int BT = in_sizes[0] / HID;     // B*T
    int T = 1024;
    int B_ = BT / T;
    size_t M = (size_t)BT;
    size_t sz_big = M * HID;
    const int nW = HID * HID;       // 1M
    const int nS = D * HID;         // 131072

    // ---- explicit workspace layout (no aliasing) ----
    float* fp = (float*)d_ws;
    float* QKVp = fp;               fp += 3 * sz_big;   // M x 3072 fused q|k|v
    float* Qc   = fp;               fp += sz_big;
    float* Kc   = fp;               fp += sz_big;
    float* Vc   = fp;               fp += sz_big;
    float* EGb  = fp;               fp += sz_big;
    float* GATE = fp;               fp += sz_big;
    float* Obuf = fp;               fp += sz_big;
    float* BETA = fp;               fp += M * H;
    bhalf* bp = (bhalf*)fp;
    bhalf* xb   = bp;               bp += sz_big;
    bhalf* Wqkvb= bp;               bp += 3 * (size_t)nW;   // Wq|Wk|Wv contiguous
    bhalf* Wob  = bp;               bp += nW;
    bhalf* Wfgab= bp;               bp += 2 * (size_t)nS;   // Wfa|Wga contiguous
    bhalf* Wfbb = bp;               bp += nS;
    bhalf* Wgbb = bp;               bp += nS;
    bhalf* XAG  = bp;               bp += M * 256;          // M x 256: xa|xg
    bhalf* Obf  = bp;               bp += sz_big;

    dim3 blk(256);

    // casts (3 launches)
    cast1<<<(int)((sz_big + 255) / 256), 256, 0, stream>>>(x, xb, (int)sz_big);
    cast4<<<dim3((nW + 255) / 256, 4), 256, 0, stream>>>(Wq, Wk, Wv, Wo,
                                                         Wqkvb, Wqkvb + nW, Wqkvb + 2 * (size_t)nW, Wob, nW);
    cast4<<<dim3((nS + 255) / 256, 4), 256, 0, stream>>>(Wfa, Wga, Wfb, Wgb,
                                                         Wfgab, Wfgab + nS, Wfbb, Wgbb, nS);

    // fused QKV projection: C[M,3072] = xb @ [Wq|Wk|Wv]^T   (768 blocks)
    gemm_bf16_nt<<<dim3(3072 / 64, BT / 128), blk, 0, stream>>>(
        xb, Wqkvb, QKVp, BT, 3072, HID, HID, HID, 3072, 0, nullptr, nullptr,
        nullptr, nullptr, nullptr, 0);

    // fused low-rank first stage: XAG[M,256] = xb @ [Wfa|Wga]^T (bf16 out)
    gemm_bf16_nt<<<dim3(256 / 64, BT / 128), blk, 0, stream>>>(
        xb, Wfgab, XAG, BT, 256, HID, HID, HID, 256, 2, nullptr, nullptr,
        nullptr, nullptr, nullptr, 0);

    beta_kernel<<<BT, 256, 0, stream>>>(x, Wb, BETA);

    // conv + silu (+norm) fused, one launch
    conv3_kernel<<<dim3(BT * H, 3), 128, 0, stream>>>(QKVp,
                                                      wq_conv, wk_conv, wv_conv,
                                                      Qc, Kc, Vc, T);

    // second stage batched (z=0: EGb w/ fused eg transform; z=1: GATE)
    gemm_bf16_nt<<<dim3(HID / 64, BT / 128, 2), blk, 0, stream>>>(
        XAG, Wfbb, EGb, BT, HID, D, 256, D, HID, 1, A_log, dt_bias,
        XAG + D, Wgbb, GATE, 0);

    // recurrence
    recur_cols_kernel<<<B_ * H * 32, 256, 0, stream>>>(Qc, Kc, Vc, EGb, BETA, Obuf, T);

    // output norm * gate -> bf16
    outnorm_kernel<<<BT * H, 128, 0, stream>>>(Obuf, GATE, o_norm_w, Obf);

    // final projection (bf16 MFMA)
    gemm_bf16_nt<<<dim3(HID / 64, BT / 128), blk, 0, stream>>>(
        Obf, Wob, (float*)d_out, BT, HID, HID, HID, HID, HID, 0, nullptr, nullptr,
        nullptr, nullptr, nullptr, 0);
}